// Round 3
// baseline (220.697 us; speedup 1.0000x reference)
//
#include <hip/hip_runtime.h>
#include <math.h>

typedef __attribute__((ext_vector_type(8))) short bf16x8;
typedef __attribute__((ext_vector_type(8))) unsigned short u16x8;
typedef __attribute__((ext_vector_type(4))) float f32x4;

#define LL    4096
#define FDIM  128
#define NLEV  12
#define EPSF  1e-5f
#define SCL   0.08838834764831845f   // 1/sqrt(128)

// ---------------- ws layout (float offsets) ----------------
#define OFF_QSUM 0          // 32*128
#define OFF_KSUM 4096
#define OFF_SSUM 8192
#define OFF_CP   12288      // 32*128 fp32 c'
#define OFF_G    16384      // fp32 G[32][128][128] = 524288 floats (atomic-accumulated)
#define OFF_MP   540672     // bf16 M'^T swizzled image: 32*16384 ushort = 262144 float slots

__device__ __forceinline__ unsigned short bfr(float f) {   // fp32 -> bf16 RTNE
    union { float f; unsigned u; } v; v.f = f;
    unsigned r = v.u + 0x7FFF + ((v.u >> 16) & 1);
    return (unsigned short)(r >> 16);
}
__device__ __forceinline__ float b2f(unsigned short u) {
    union { float f; unsigned u; } v; v.u = ((unsigned)u) << 16; return v.f;
}
// XOR swizzle of 16B slots within a row (slot count = row_bytes/16).
__device__ __forceinline__ int swz(int row, int kblk) {
    return kblk ^ (row & 7) ^ ((row >> 3) & 7);
}
__device__ __forceinline__ void ldsload16(void* lds, const void* g) {
    __builtin_amdgcn_global_load_lds((const __attribute__((address_space(1))) unsigned int*)g,
                                     (__attribute__((address_space(3))) unsigned int*)lds, 16, 0, 0);
}

// ---------------------------------------------------------------- pass1
// grid (32, 32), 256 threads: 128-row chunk per block.
// Produces: q/k/plain colsums (atomic), fp32 Gram tile (atomic into G).
__global__ __launch_bounds__(256) void pass1_kernel(const float* __restrict__ x,
                                                    const float* __restrict__ qw,
                                                    const float* __restrict__ kw,
                                                    float* __restrict__ ws) {
    __shared__ __align__(16) unsigned short XT[16384];   // 32KB: [f][k0..127] bf16, slot-swizzled
    __shared__ float cq[128], ck[128];
    const int b = blockIdx.y, c0 = blockIdx.x * 128;
    const int tid = threadIdx.x;
    {   // per-row wavelet coefficients (fused coeff_kernel)
        int row = c0 + (tid & 127);
        float pq = 1.f, pk = 1.f;
#pragma unroll
        for (int i = 0; i < NLEV; i++) {
            int bit = (row >> i) & 1;
            pq *= qw[2 * i + bit];
            pk *= kw[2 * i + bit];
        }
        if (tid < 128) { cq[tid] = pq; ck[tid] = pk; }
    }
    __syncthreads();
    const int f0 = (tid & 31) * 4;
    const int rh = tid >> 5;                    // 0..7
    const int wave = tid >> 6, lane = tid & 63, l15 = lane & 15, quad = lane >> 4;
    const float* Xg = x + ((size_t)b * LL + c0) * FDIM;
    f32x4 aq = {0,0,0,0}, ak = {0,0,0,0}, asv = {0,0,0,0};
#pragma unroll
    for (int g = 0; g < 2; g++) {
        const int lb = g * 64 + rh * 8;         // 8 consecutive rows per thread
        float4 v[8];
#pragma unroll
        for (int s = 0; s < 8; s++) v[s] = *(const float4*)&Xg[(size_t)(lb + s) * FDIM + f0];
        u16x8 hj[4];                            // transpose-pack: hj[j][s] = bf16(X[lb+s][f0+j])
#pragma unroll
        for (int s = 0; s < 8; s++) {
            float wq = cq[lb + s], wk = ck[lb + s];
            aq[0] += wq * v[s].x; aq[1] += wq * v[s].y; aq[2] += wq * v[s].z; aq[3] += wq * v[s].w;
            ak[0] += wk * v[s].x; ak[1] += wk * v[s].y; ak[2] += wk * v[s].z; ak[3] += wk * v[s].w;
            asv[0] += v[s].x; asv[1] += v[s].y; asv[2] += v[s].z; asv[3] += v[s].w;
            hj[0][s] = bfr(v[s].x); hj[1][s] = bfr(v[s].y);
            hj[2][s] = bfr(v[s].z); hj[3][s] = bfr(v[s].w);
        }
#pragma unroll
        for (int j = 0; j < 4; j++) {           // b128 write: 8 l's of row f0+j
            int f = f0 + j;
            *(u16x8*)((char*)XT + f * 256 + (swz(f, g * 8 + rh) << 4)) = hj[j];
        }
    }
    __syncthreads();
    // Gram accumulate over K=128 (4 phases)
    f32x4 acc[2][8];
#pragma unroll
    for (int i = 0; i < 2; i++)
#pragma unroll
        for (int n = 0; n < 8; n++) acc[i][n] = (f32x4){0,0,0,0};
#pragma unroll
    for (int k0 = 0; k0 < 128; k0 += 32) {
        bf16x8 a[2];
#pragma unroll
        for (int i = 0; i < 2; i++) {
            int fa = (wave * 2 + i) * 16 + l15;
            a[i] = *(const bf16x8*)((const char*)XT + fa * 256 + (swz(fa, (k0 >> 3) + quad) << 4));
        }
#pragma unroll
        for (int n = 0; n < 8; n++) {
            int gb = n * 16 + l15;
            bf16x8 bb = *(const bf16x8*)((const char*)XT + gb * 256 + (swz(gb, (k0 >> 3) + quad) << 4));
            acc[0][n] = __builtin_amdgcn_mfma_f32_16x16x32_bf16(a[0], bb, acc[0][n], 0, 0, 0);
            acc[1][n] = __builtin_amdgcn_mfma_f32_16x16x32_bf16(a[1], bb, acc[1][n], 0, 0, 0);
        }
    }
    __syncthreads();
    // colsum scratch (reuse XT) + Gram atomics
    float* red = (float*)XT;
    *(f32x4*)&red[0 * 1056 + rh * 132 + f0] = aq;
    *(f32x4*)&red[1 * 1056 + rh * 132 + f0] = ak;
    *(f32x4*)&red[2 * 1056 + rh * 132 + f0] = asv;
    float* Gg = ws + OFF_G + (size_t)b * 16384;
#pragma unroll
    for (int i = 0; i < 2; i++)
#pragma unroll
        for (int n = 0; n < 8; n++) {
            int g = n * 16 + l15;
#pragma unroll
            for (int reg = 0; reg < 4; reg++) {
                int f = (wave * 2 + i) * 16 + quad * 4 + reg;
                atomicAdd(&Gg[f * 128 + g], acc[i][n][reg]);
            }
        }
    __syncthreads();
    if (tid < 128) {
#pragma unroll
        for (int p = 0; p < 3; p++) {
            float s = 0.f;
#pragma unroll
            for (int r = 0; r < 8; r++) s += red[p * 1056 + r * 132 + tid];
            atomicAdd(&ws[(p == 0 ? OFF_QSUM : p == 1 ? OFF_KSUM : OFF_SSUM) + b * FDIM + tid], s);
        }
    }
}

// ---------------------------------------------------------------- solve: per-batch fold to M', c'
// grid 32, 256 threads. Stages fp32 G -> split-bf16 in LDS.
__global__ __launch_bounds__(256) void solve_kernel(const float* __restrict__ qw,
                                                    const float* __restrict__ qb,
                                                    const float* __restrict__ kw,
                                                    const float* __restrict__ kb,
                                                    const float* __restrict__ ffw,
                                                    const float* __restrict__ ffb,
                                                    const float* __restrict__ gamma,
                                                    const float* __restrict__ beta,
                                                    float* __restrict__ ws) {
    __shared__ __align__(16) unsigned short GhL[16384];
    __shared__ __align__(16) unsigned short GlL[16384];
    __shared__ __align__(16) unsigned short SA[16384];   // M1 row-major; later M2^T
    __shared__ __align__(16) unsigned short SB[16384];   // M1^T; later diag(a1)(I+W^T) image
    __shared__ float scr_k[128], scr_s[128], scr_a1[128], scr_b1[128], scr_a2[128];
    __shared__ float scr_vs[512];
    __shared__ float scr_mm[4];
    const int b = blockIdx.x, tid = threadIdx.x;
    const int wave = tid >> 6, lane = tid & 63, l15 = lane & 15, quad = lane >> 4;

    // ---- stage G (fp32, atomic-summed) -> split bf16 in LDS (swizzled)
    {
        const float* Gg = ws + OFF_G + (size_t)b * 16384;
        const int fG = tid >> 5, g0 = (tid & 31) * 4;
#pragma unroll 4
        for (int i = 0; i < 16; i++) {
            float4 u = *(const float4*)&Gg[i * 1024 + tid * 4];
            ushort4 gh, gl;
            gh.x = bfr(u.x); gl.x = bfr(u.x - b2f(gh.x));
            gh.y = bfr(u.y); gl.y = bfr(u.y - b2f(gh.y));
            gh.z = bfr(u.z); gl.z = bfr(u.z - b2f(gh.z));
            gh.w = bfr(u.w); gl.w = bfr(u.w - b2f(gh.w));
            int f = i * 8 + fG;
            int byte = f * 256 + (swz(f, g0 >> 3) << 4) + (g0 & 4) * 2;
            *(ushort4*)((char*)GhL + byte) = gh;
            *(ushort4*)((char*)GlL + byte) = gl;
        }
    }
    // dq/dk (uniform recurrence)
    float dq = 0.f, dk = 0.f;
#pragma unroll
    for (int i = 0; i < NLEV; i++) {
        dq = (qw[2 * i] + qw[2 * i + 1]) * dq + qb[i];
        dk = (kw[2 * i] + kw[2 * i + 1]) * dk + kb[i];
    }
    float qf = 0.f, kf = 0.f;
    if (tid < 128) {
        qf = (ws[OFF_QSUM + b * FDIM + tid] + dq) * SCL;
        kf = ws[OFF_KSUM + b * FDIM + tid] + dk;
        scr_k[tid] = kf;
        scr_s[tid] = ws[OFF_SSUM + b * FDIM + tid];
        float mx = kf, mn = kf;
#pragma unroll
        for (int off = 32; off; off >>= 1) {
            mx = fmaxf(mx, __shfl_xor(mx, off, 64));
            mn = fminf(mn, __shfl_xor(mn, off, 64));
        }
        if (lane == 0) { scr_mm[wave * 2] = mx; scr_mm[wave * 2 + 1] = mn; }
    }
    __syncthreads();
    float kmax = fmaxf(scr_mm[0], scr_mm[2]);
    float kmin = fminf(scr_mm[1], scr_mm[3]);

    // att: rank-1 scores -> softmax rows, fold +I; SA = M1 row-major, SB = M1^T
    if (tid < 128) {
        const int f = tid;
        float m = (qf >= 0.f) ? qf * kmax : qf * kmin;
        float ssum = 0.f;
        for (int gi = 0; gi < 16; gi++) {
            u16x8 h;
#pragma unroll
            for (int j = 0; j < 8; j++) {
                float e = __expf(qf * scr_k[gi * 8 + j] - m);
                ssum += e;
                h[j] = bfr(e);
            }
            *(u16x8*)((char*)SA + f * 256 + (swz(f, gi) << 4)) = h;
        }
        float sinv = 1.f / ssum;
        for (int gi = 0; gi < 16; gi++) {
            char* pa = (char*)SA + f * 256 + (swz(f, gi) << 4);
            u16x8 h = *(u16x8*)pa;
#pragma unroll
            for (int j = 0; j < 8; j++) {
                int g = gi * 8 + j;
                float v = b2f(h[j]) * sinv;
                if (g == f) v += 1.f;
                unsigned short u = bfr(v);
                h[j] = u;
                *(unsigned short*)((char*)SB + g * 256 + (swz(g, f >> 3) << 4) + (f & 7) * 2) = u;
            }
            *(u16x8*)pa = h;
        }
    }
    __syncthreads();

    // ---- P1 = (Gh+Gl) * M1 ; varsum1_g = diag(M1^T G M1)
    {
        f32x4 acc[2][8];
#pragma unroll
        for (int i = 0; i < 2; i++)
#pragma unroll
            for (int n = 0; n < 8; n++) acc[i][n] = (f32x4){0,0,0,0};
        for (int k0 = 0; k0 < 128; k0 += 32) {
            bf16x8 aH[2], aL[2];
#pragma unroll
            for (int i = 0; i < 2; i++) {
                int fa = (wave * 2 + i) * 16 + l15;
                int byte = fa * 256 + (swz(fa, (k0 >> 3) + quad) << 4);
                aH[i] = *(const bf16x8*)((const char*)GhL + byte);
                aL[i] = *(const bf16x8*)((const char*)GlL + byte);
            }
#pragma unroll
            for (int n = 0; n < 8; n++) {
                int gb = n * 16 + l15;
                bf16x8 bb = *(const bf16x8*)((const char*)SB + gb * 256 + (swz(gb, (k0 >> 3) + quad) << 4));
#pragma unroll
                for (int i = 0; i < 2; i++) {
                    acc[i][n] = __builtin_amdgcn_mfma_f32_16x16x32_bf16(aH[i], bb, acc[i][n], 0, 0, 0);
                    acc[i][n] = __builtin_amdgcn_mfma_f32_16x16x32_bf16(aL[i], bb, acc[i][n], 0, 0, 0);
                }
            }
        }
        float vsp[8];
#pragma unroll
        for (int n = 0; n < 8; n++) vsp[n] = 0.f;
#pragma unroll
        for (int i = 0; i < 2; i++)
#pragma unroll
            for (int n = 0; n < 8; n++) {
                int g = n * 16 + l15;
#pragma unroll
                for (int reg = 0; reg < 4; reg++) {
                    int f = (wave * 2 + i) * 16 + quad * 4 + reg;
                    float m1 = b2f(*(const unsigned short*)((const char*)SA + f * 256 + (swz(f, g >> 3) << 4) + (g & 7) * 2));
                    vsp[n] += m1 * acc[i][n][reg];
                }
            }
#pragma unroll
        for (int n = 0; n < 8; n++) {
            float v = vsp[n];
            v += __shfl_xor(v, 16, 64); v += __shfl_xor(v, 32, 64);
            if (lane < 16) scr_vs[wave * 128 + n * 16 + lane] = v;
        }
    }
    __syncthreads();
    // stats1 -> a1, b1
    if (tid < 128) {
        const int g = tid;
        float vs = scr_vs[g] + scr_vs[128 + g] + scr_vs[256 + g] + scr_vs[384 + g];
        float tg = 0.f;
        for (int fb = 0; fb < 16; fb++) {
            u16x8 h = *(const u16x8*)((const char*)SB + g * 256 + (swz(g, fb) << 4));
#pragma unroll
            for (int j = 0; j < 8; j++) tg += scr_s[fb * 8 + j] * b2f(h[j]);
        }
        float mean = tg * (1.f / LL);
        float var  = vs * (1.f / LL) - mean * mean;
        float a1 = gamma[g] * rsqrtf(var + EPSF);
        scr_a1[g] = a1;
        scr_b1[g] = beta[g] - mean * a1;
    }
    __syncthreads();
    // stage SB = [diag(a1)(I+W^T)]^T image: SB[g][h] = a1_h * (W[g][h] + (g==h))
#pragma unroll
    for (int i = 0; i < 16; i++) {
        int idx4 = (tid + i * 256) * 4;
        int g = idx4 >> 7, h0 = idx4 & 127;
        float4 w = *(const float4*)&ffw[g * FDIM + h0];
        float v0 = (w.x + ((g == h0 + 0) ? 1.f : 0.f)) * scr_a1[h0 + 0];
        float v1 = (w.y + ((g == h0 + 1) ? 1.f : 0.f)) * scr_a1[h0 + 1];
        float v2 = (w.z + ((g == h0 + 2) ? 1.f : 0.f)) * scr_a1[h0 + 2];
        float v3 = (w.w + ((g == h0 + 3) ? 1.f : 0.f)) * scr_a1[h0 + 3];
        ushort4 h; h.x = bfr(v0); h.y = bfr(v1); h.z = bfr(v2); h.w = bfr(v3);
        *(ushort4*)((char*)SB + g * 256 + (swz(g, h0 >> 3) << 4) + (h0 & 7) * 2) = h;
    }
    __syncthreads();
    // ---- M2 = M1 * diag(a1)(I+W^T)
    {
        f32x4 accM[2][8];
#pragma unroll
        for (int i = 0; i < 2; i++)
#pragma unroll
            for (int n = 0; n < 8; n++) accM[i][n] = (f32x4){0,0,0,0};
        for (int k0 = 0; k0 < 128; k0 += 32) {
            bf16x8 a[2];
#pragma unroll
            for (int i = 0; i < 2; i++) {
                int fa = (wave * 2 + i) * 16 + l15;
                a[i] = *(const bf16x8*)((const char*)SA + fa * 256 + (swz(fa, (k0 >> 3) + quad) << 4));
            }
#pragma unroll
            for (int n = 0; n < 8; n++) {
                int gb = n * 16 + l15;
                bf16x8 bb = *(const bf16x8*)((const char*)SB + gb * 256 + (swz(gb, (k0 >> 3) + quad) << 4));
#pragma unroll
                for (int i = 0; i < 2; i++)
                    accM[i][n] = __builtin_amdgcn_mfma_f32_16x16x32_bf16(a[i], bb, accM[i][n], 0, 0, 0);
            }
        }
        __syncthreads();           // all M1 reads done; overwrite SA with M2^T
#pragma unroll
        for (int i = 0; i < 2; i++)
#pragma unroll
            for (int n = 0; n < 8; n++) {
                int g = n * 16 + l15;
#pragma unroll
                for (int reg = 0; reg < 4; reg++) {
                    int f = (wave * 2 + i) * 16 + quad * 4 + reg;
                    *(unsigned short*)((char*)SA + g * 256 + (swz(g, f >> 3) << 4) + (f & 7) * 2) = bfr(accM[i][n][reg]);
                }
            }
    }
    __syncthreads();
    // ---- P2 = (Gh+Gl) * M2 ; varsum2_g = diag(M2^T G M2)
    {
        f32x4 acc[2][8];
#pragma unroll
        for (int i = 0; i < 2; i++)
#pragma unroll
            for (int n = 0; n < 8; n++) acc[i][n] = (f32x4){0,0,0,0};
        for (int k0 = 0; k0 < 128; k0 += 32) {
            bf16x8 aH[2], aL[2];
#pragma unroll
            for (int i = 0; i < 2; i++) {
                int fa = (wave * 2 + i) * 16 + l15;
                int byte = fa * 256 + (swz(fa, (k0 >> 3) + quad) << 4);
                aH[i] = *(const bf16x8*)((const char*)GhL + byte);
                aL[i] = *(const bf16x8*)((const char*)GlL + byte);
            }
#pragma unroll
            for (int n = 0; n < 8; n++) {
                int gb = n * 16 + l15;
                bf16x8 bb = *(const bf16x8*)((const char*)SA + gb * 256 + (swz(gb, (k0 >> 3) + quad) << 4));
#pragma unroll
                for (int i = 0; i < 2; i++) {
                    acc[i][n] = __builtin_amdgcn_mfma_f32_16x16x32_bf16(aH[i], bb, acc[i][n], 0, 0, 0);
                    acc[i][n] = __builtin_amdgcn_mfma_f32_16x16x32_bf16(aL[i], bb, acc[i][n], 0, 0, 0);
                }
            }
        }
        float vsp[8];
#pragma unroll
        for (int n = 0; n < 8; n++) vsp[n] = 0.f;
#pragma unroll
        for (int i = 0; i < 2; i++)
#pragma unroll
            for (int n = 0; n < 8; n++) {
                int g = n * 16 + l15;
#pragma unroll
                for (int reg = 0; reg < 4; reg++) {
                    int f = (wave * 2 + i) * 16 + quad * 4 + reg;
                    float m2 = b2f(*(const unsigned short*)((const char*)SA + g * 256 + (swz(g, f >> 3) << 4) + (f & 7) * 2));
                    vsp[n] += m2 * acc[i][n][reg];
                }
            }
#pragma unroll
        for (int n = 0; n < 8; n++) {
            float v = vsp[n];
            v += __shfl_xor(v, 16, 64); v += __shfl_xor(v, 32, 64);
            if (lane < 16) scr_vs[wave * 128 + n * 16 + lane] = v;
        }
    }
    __syncthreads();
    // stats2 -> a2, c'
    if (tid < 128) {
        const int g = tid;
        float vs = scr_vs[g] + scr_vs[128 + g] + scr_vs[256 + g] + scr_vs[384 + g];
        float t2 = 0.f;
        for (int fb = 0; fb < 16; fb++) {
            u16x8 h = *(const u16x8*)((const char*)SA + g * 256 + (swz(g, fb) << 4));
#pragma unroll
            for (int j = 0; j < 8; j++) t2 += scr_s[fb * 8 + j] * b2f(h[j]);
        }
        float c2 = ffb[g] + scr_b1[g];
        for (int hb = 0; hb < 32; hb++) {
            float4 w = *(const float4*)&ffw[g * FDIM + hb * 4];
            c2 += scr_b1[hb * 4 + 0] * w.x + scr_b1[hb * 4 + 1] * w.y
                + scr_b1[hb * 4 + 2] * w.z + scr_b1[hb * 4 + 3] * w.w;
        }
        float mean2 = t2 * (1.f / LL) + c2;
        float ey2   = vs * (1.f / LL) + 2.f * c2 * t2 * (1.f / LL) + c2 * c2;
        float var2  = ey2 - mean2 * mean2;
        float a2 = gamma[g] * rsqrtf(var2 + EPSF);
        scr_a2[g] = a2;
        ws[OFF_CP + b * FDIM + g] = a2 * (c2 - mean2) + beta[g];
    }
    __syncthreads();
    // M'^T = a2-scaled M2^T -> global MP (same swizzled byte image as LDS)
    {
        unsigned short* MP = (unsigned short*)(ws + OFF_MP) + (size_t)b * 16384;
        const int g = tid >> 1, half = (tid & 1) * 8;
        float a2 = scr_a2[g];
        for (int s = 0; s < 8; s++) {
            int slot = half + s;
            u16x8 h = *(const u16x8*)((const char*)SA + g * 256 + slot * 16);
#pragma unroll
            for (int j = 0; j < 8; j++) h[j] = bfr(b2f(h[j]) * a2);
            *(u16x8*)&MP[g * 128 + slot * 8] = h;
        }
    }
}

// ---------------------------------------------------------------- out = X * M' + c'
// grid (64, 32), 256 threads, 64-row tiles; X fp32 (L3-hot), M' via LDS DMA.
__global__ __launch_bounds__(256) void outgemm_kernel(const float* __restrict__ x,
                                                      const float* __restrict__ ws,
                                                      float* __restrict__ out) {
    __shared__ __align__(16) unsigned short Xs[64][136];
    __shared__ __align__(16) unsigned short Bs[16384];
    __shared__ float cps[128];
    const int b = blockIdx.y, r0 = blockIdx.x * 64, tid = threadIdx.x;
    const char* mp = (const char*)ws + (size_t)OFF_MP * 4 + (size_t)b * 32768;
#pragma unroll
    for (int i = 0; i < 8; i++)
        ldsload16((char*)Bs + i * 4096 + tid * 16, mp + i * 4096 + tid * 16);
    const float* Xg = x + (size_t)b * LL * FDIM + (size_t)r0 * FDIM;
#pragma unroll
    for (int i = 0; i < 8; i++) {
        int idx4 = (tid + i * 256) * 4;
        int r = idx4 >> 7, c = idx4 & 127;
        float4 v = *(const float4*)&Xg[r * FDIM + c];
        ushort4 h; h.x = bfr(v.x); h.y = bfr(v.y); h.z = bfr(v.z); h.w = bfr(v.w);
        *(ushort4*)&Xs[r][c] = h;
    }
    if (tid < 128) cps[tid] = ws[OFF_CP + b * FDIM + tid];
    __syncthreads();
    const int wave = tid >> 6, lane = tid & 63, l15 = lane & 15, quad = lane >> 4;
    const int rowA = wave * 16 + l15;
    f32x4 acc[8];
#pragma unroll
    for (int t = 0; t < 8; t++) acc[t] = (f32x4){0,0,0,0};
#pragma unroll
    for (int k0 = 0; k0 < 128; k0 += 32) {
        bf16x8 a = *(const bf16x8*)&Xs[rowA][k0 + quad * 8];
#pragma unroll
        for (int t = 0; t < 8; t++) {
            int gb = t * 16 + l15;
            bf16x8 bb = *(const bf16x8*)((const char*)Bs + gb * 256 + (swz(gb, (k0 >> 3) + quad) << 4));
            acc[t] = __builtin_amdgcn_mfma_f32_16x16x32_bf16(a, bb, acc[t], 0, 0, 0);
        }
    }
    float* Ob = out + ((size_t)b * LL + r0) * FDIM;
#pragma unroll
    for (int t = 0; t < 8; t++) {
        int col = t * 16 + l15;
        float cp = cps[col];
#pragma unroll
        for (int reg = 0; reg < 4; reg++)
            Ob[(wave * 16 + quad * 4 + reg) * FDIM + col] = acc[t][reg] + cp;
    }
}

extern "C" void kernel_launch(void* const* d_in, const int* in_sizes, int n_in,
                              void* d_out, int out_size, void* d_ws, size_t ws_size,
                              hipStream_t stream) {
    const float* x     = (const float*)d_in[0];
    const float* q_w   = (const float*)d_in[1];
    const float* q_b   = (const float*)d_in[2];
    const float* k_w   = (const float*)d_in[3];
    const float* k_b   = (const float*)d_in[4];
    const float* ff_w  = (const float*)d_in[5];
    const float* ff_b  = (const float*)d_in[6];
    const float* gamma = (const float*)d_in[7];
    const float* beta  = (const float*)d_in[8];
    float* out = (float*)d_out;
    float* ws  = (float*)d_ws;

    // zero qsum/ksum/ssum (+cp harmlessly) and the fp32 G accumulator
    hipMemsetAsync(ws, 0, (size_t)(OFF_MP) * sizeof(float), stream);
    pass1_kernel<<<dim3(32, 32), 256, 0, stream>>>(x, q_w, k_w, ws);
    solve_kernel<<<32, 256, 0, stream>>>(q_w, q_b, k_w, k_b, ff_w, ff_b, gamma, beta, ws);
    outgemm_kernel<<<dim3(64, 32), 256, 0, stream>>>(x, ws, out);
}

// Round 4
// 183.008 us; speedup vs baseline: 1.2059x; 1.2059x over previous
//
#include <hip/hip_runtime.h>
#include <math.h>

typedef __attribute__((ext_vector_type(8))) short bf16x8;
typedef __attribute__((ext_vector_type(8))) unsigned short u16x8;
typedef __attribute__((ext_vector_type(4))) float f32x4;

#define LL    4096
#define FDIM  128
#define NLEV  12
#define EPSF  1e-5f
#define SCL   0.08838834764831845f   // 1/sqrt(128)

// ---------------- ws layout (float offsets) ----------------
#define OFF_QSUM 0          // 32*128
#define OFF_KSUM 4096
#define OFF_SSUM 8192
#define OFF_CP   12288      // 32*128 fp32 c'
#define OFF_G    16384      // fp32 G[32][128][128] = 524288 floats (written by reduce)
#define OFF_MP   540672     // bf16 M'^T swizzled image: 32*16384 ushort = 262144 float slots
#define OFF_GP   802816     // fp32 Gram partials: 16 chunks * 524288 = 8388608 floats

__device__ __forceinline__ unsigned short bfr(float f) {   // fp32 -> bf16 RTNE
    union { float f; unsigned u; } v; v.f = f;
    unsigned r = v.u + 0x7FFF + ((v.u >> 16) & 1);
    return (unsigned short)(r >> 16);
}
__device__ __forceinline__ float b2f(unsigned short u) {
    union { float f; unsigned u; } v; v.u = ((unsigned)u) << 16; return v.f;
}
// XOR swizzle of 16B slots within a row (slot count = row_bytes/16).
__device__ __forceinline__ int swz(int row, int kblk) {
    return kblk ^ (row & 7) ^ ((row >> 3) & 7);
}
__device__ __forceinline__ void ldsload16(void* lds, const void* g) {
    __builtin_amdgcn_global_load_lds((const __attribute__((address_space(1))) unsigned int*)g,
                                     (__attribute__((address_space(3))) unsigned int*)lds, 16, 0, 0);
}

// ---------------------------------------------------------------- pass1
// grid (16, 32), 256 threads: 256-row chunk per block, two 128-row stages
// through one 32KB LDS buffer. Produces q/k/plain colsums (atomic) and a
// streaming fp32 Gram partial (no atomics).
__global__ __launch_bounds__(256) void pass1_kernel(const float* __restrict__ x,
                                                    const float* __restrict__ qw,
                                                    const float* __restrict__ kw,
                                                    float* __restrict__ ws) {
    __shared__ __align__(16) unsigned short XT[16384];   // 32KB: [f][k0..127] bf16, slot-swizzled
    __shared__ float cq[256], ck[256];
    const int b = blockIdx.y, c0 = blockIdx.x * 256;
    const int tid = threadIdx.x;
    {   // per-row wavelet coefficients (fused coeff_kernel)
        int row = c0 + tid;
        float pq = 1.f, pk = 1.f;
#pragma unroll
        for (int i = 0; i < NLEV; i++) {
            int bit = (row >> i) & 1;
            pq *= qw[2 * i + bit];
            pk *= kw[2 * i + bit];
        }
        cq[tid] = pq; ck[tid] = pk;
    }
    __syncthreads();
    const int f0 = (tid & 31) * 4;
    const int rh = tid >> 5;                    // 0..7
    const int wave = tid >> 6, lane = tid & 63, l15 = lane & 15, quad = lane >> 4;
    f32x4 aq = {0,0,0,0}, ak = {0,0,0,0}, asv = {0,0,0,0};
    f32x4 acc[2][8];
#pragma unroll
    for (int i = 0; i < 2; i++)
#pragma unroll
        for (int n = 0; n < 8; n++) acc[i][n] = (f32x4){0,0,0,0};

    for (int stage = 0; stage < 2; stage++) {
        const float* Xg = x + ((size_t)b * LL + c0 + stage * 128) * FDIM;
#pragma unroll
        for (int g = 0; g < 2; g++) {
            const int lb = g * 64 + rh * 8;     // 8 consecutive rows per thread
            float4 v[8];
#pragma unroll
            for (int s = 0; s < 8; s++) v[s] = *(const float4*)&Xg[(size_t)(lb + s) * FDIM + f0];
            u16x8 hj[4];                        // transpose-pack: hj[j][s] = bf16(X[lb+s][f0+j])
#pragma unroll
            for (int s = 0; s < 8; s++) {
                int ci = stage * 128 + lb + s;
                float wq = cq[ci], wk = ck[ci];
                aq[0] += wq * v[s].x; aq[1] += wq * v[s].y; aq[2] += wq * v[s].z; aq[3] += wq * v[s].w;
                ak[0] += wk * v[s].x; ak[1] += wk * v[s].y; ak[2] += wk * v[s].z; ak[3] += wk * v[s].w;
                asv[0] += v[s].x; asv[1] += v[s].y; asv[2] += v[s].z; asv[3] += v[s].w;
                hj[0][s] = bfr(v[s].x); hj[1][s] = bfr(v[s].y);
                hj[2][s] = bfr(v[s].z); hj[3][s] = bfr(v[s].w);
            }
#pragma unroll
            for (int j = 0; j < 4; j++) {       // b128 write: 8 l's of row f0+j
                int f = f0 + j;
                *(u16x8*)((char*)XT + f * 256 + (swz(f, g * 8 + rh) << 4)) = hj[j];
            }
        }
        __syncthreads();
        // Gram accumulate over this stage's K=128 (4 phases)
#pragma unroll
        for (int k0 = 0; k0 < 128; k0 += 32) {
            bf16x8 a[2];
#pragma unroll
            for (int i = 0; i < 2; i++) {
                int fa = (wave * 2 + i) * 16 + l15;
                a[i] = *(const bf16x8*)((const char*)XT + fa * 256 + (swz(fa, (k0 >> 3) + quad) << 4));
            }
#pragma unroll
            for (int n = 0; n < 8; n++) {
                int gb = n * 16 + l15;
                bf16x8 bb = *(const bf16x8*)((const char*)XT + gb * 256 + (swz(gb, (k0 >> 3) + quad) << 4));
                acc[0][n] = __builtin_amdgcn_mfma_f32_16x16x32_bf16(a[0], bb, acc[0][n], 0, 0, 0);
                acc[1][n] = __builtin_amdgcn_mfma_f32_16x16x32_bf16(a[1], bb, acc[1][n], 0, 0, 0);
            }
        }
        __syncthreads();
    }
    // streaming Gram partial store (16 chunks/batch, no contention)
    float* Gp = ws + OFF_GP + ((size_t)blockIdx.x * 32 + b) * 16384;
#pragma unroll
    for (int i = 0; i < 2; i++)
#pragma unroll
        for (int n = 0; n < 8; n++) {
            int g = n * 16 + l15;
#pragma unroll
            for (int reg = 0; reg < 4; reg++) {
                int f = (wave * 2 + i) * 16 + quad * 4 + reg;
                Gp[f * 128 + g] = acc[i][n][reg];
            }
        }
    // colsum reductions, reusing XT as float scratch [3][8][132]
    float* red = (float*)XT;
    *(f32x4*)&red[0 * 1056 + rh * 132 + f0] = aq;
    *(f32x4*)&red[1 * 1056 + rh * 132 + f0] = ak;
    *(f32x4*)&red[2 * 1056 + rh * 132 + f0] = asv;
    __syncthreads();
    if (tid < 128) {
#pragma unroll
        for (int p = 0; p < 3; p++) {
            float s = 0.f;
#pragma unroll
            for (int r = 0; r < 8; r++) s += red[p * 1056 + r * 132 + tid];
            atomicAdd(&ws[(p == 0 ? OFF_QSUM : p == 1 ? OFF_KSUM : OFF_SSUM) + b * FDIM + tid], s);
        }
    }
}

// ---------------------------------------------------------------- reduce: 16 partials -> fp32 G
// grid 512, 256 threads, 4 entries (1 float4) per thread. Pure streaming.
__global__ __launch_bounds__(256) void reduce_kernel(float* __restrict__ ws) {
    const size_t e0 = (size_t)blockIdx.x * 1024 + threadIdx.x * 4;
    const float* Gp = ws + OFF_GP;
    f32x4 s = {0.f, 0.f, 0.f, 0.f};
#pragma unroll
    for (int c = 0; c < 16; c++) {
        float4 u = *(const float4*)&Gp[(size_t)c * 524288 + e0];
        s[0] += u.x; s[1] += u.y; s[2] += u.z; s[3] += u.w;
    }
    *(f32x4*)&ws[OFF_G + e0] = s;
}

// ---------------------------------------------------------------- solve: per-batch fold to M', c'
// grid 32, 256 threads. Stages fp32 G -> split-bf16 in LDS.
__global__ __launch_bounds__(256) void solve_kernel(const float* __restrict__ qw,
                                                    const float* __restrict__ qb,
                                                    const float* __restrict__ kw,
                                                    const float* __restrict__ kb,
                                                    const float* __restrict__ ffw,
                                                    const float* __restrict__ ffb,
                                                    const float* __restrict__ gamma,
                                                    const float* __restrict__ beta,
                                                    float* __restrict__ ws) {
    __shared__ __align__(16) unsigned short GhL[16384];
    __shared__ __align__(16) unsigned short GlL[16384];
    __shared__ __align__(16) unsigned short SA[16384];   // M1 row-major; later M2^T
    __shared__ __align__(16) unsigned short SB[16384];   // M1^T; later diag(a1)(I+W^T) image
    __shared__ float scr_k[128], scr_s[128], scr_a1[128], scr_b1[128], scr_a2[128];
    __shared__ float scr_vs[512];
    __shared__ float scr_mm[4];
    const int b = blockIdx.x, tid = threadIdx.x;
    const int wave = tid >> 6, lane = tid & 63, l15 = lane & 15, quad = lane >> 4;

    // ---- stage G (fp32) -> split bf16 in LDS (swizzled)
    {
        const float* Gg = ws + OFF_G + (size_t)b * 16384;
        const int fG = tid >> 5, g0 = (tid & 31) * 4;
#pragma unroll 4
        for (int i = 0; i < 16; i++) {
            float4 u = *(const float4*)&Gg[i * 1024 + tid * 4];
            ushort4 gh, gl;
            gh.x = bfr(u.x); gl.x = bfr(u.x - b2f(gh.x));
            gh.y = bfr(u.y); gl.y = bfr(u.y - b2f(gh.y));
            gh.z = bfr(u.z); gl.z = bfr(u.z - b2f(gh.z));
            gh.w = bfr(u.w); gl.w = bfr(u.w - b2f(gh.w));
            int f = i * 8 + fG;
            int byte = f * 256 + (swz(f, g0 >> 3) << 4) + (g0 & 4) * 2;
            *(ushort4*)((char*)GhL + byte) = gh;
            *(ushort4*)((char*)GlL + byte) = gl;
        }
    }
    // dq/dk (uniform recurrence)
    float dq = 0.f, dk = 0.f;
#pragma unroll
    for (int i = 0; i < NLEV; i++) {
        dq = (qw[2 * i] + qw[2 * i + 1]) * dq + qb[i];
        dk = (kw[2 * i] + kw[2 * i + 1]) * dk + kb[i];
    }
    float qf = 0.f, kf = 0.f;
    if (tid < 128) {
        qf = (ws[OFF_QSUM + b * FDIM + tid] + dq) * SCL;
        kf = ws[OFF_KSUM + b * FDIM + tid] + dk;
        scr_k[tid] = kf;
        scr_s[tid] = ws[OFF_SSUM + b * FDIM + tid];
        float mx = kf, mn = kf;
#pragma unroll
        for (int off = 32; off; off >>= 1) {
            mx = fmaxf(mx, __shfl_xor(mx, off, 64));
            mn = fminf(mn, __shfl_xor(mn, off, 64));
        }
        if (lane == 0) { scr_mm[wave * 2] = mx; scr_mm[wave * 2 + 1] = mn; }
    }
    __syncthreads();
    float kmax = fmaxf(scr_mm[0], scr_mm[2]);
    float kmin = fminf(scr_mm[1], scr_mm[3]);

    // att: rank-1 scores -> softmax rows, fold +I; SA = M1 row-major, SB = M1^T
    if (tid < 128) {
        const int f = tid;
        float m = (qf >= 0.f) ? qf * kmax : qf * kmin;
        float ssum = 0.f;
        for (int gi = 0; gi < 16; gi++) {
            u16x8 h;
#pragma unroll
            for (int j = 0; j < 8; j++) {
                float e = __expf(qf * scr_k[gi * 8 + j] - m);
                ssum += e;
                h[j] = bfr(e);
            }
            *(u16x8*)((char*)SA + f * 256 + (swz(f, gi) << 4)) = h;
        }
        float sinv = 1.f / ssum;
        for (int gi = 0; gi < 16; gi++) {
            char* pa = (char*)SA + f * 256 + (swz(f, gi) << 4);
            u16x8 h = *(u16x8*)pa;
#pragma unroll
            for (int j = 0; j < 8; j++) {
                int g = gi * 8 + j;
                float v = b2f(h[j]) * sinv;
                if (g == f) v += 1.f;
                unsigned short u = bfr(v);
                h[j] = u;
                *(unsigned short*)((char*)SB + g * 256 + (swz(g, f >> 3) << 4) + (f & 7) * 2) = u;
            }
            *(u16x8*)pa = h;
        }
    }
    __syncthreads();

    // ---- P1 = (Gh+Gl) * M1 ; varsum1_g = diag(M1^T G M1)
    {
        f32x4 acc[2][8];
#pragma unroll
        for (int i = 0; i < 2; i++)
#pragma unroll
            for (int n = 0; n < 8; n++) acc[i][n] = (f32x4){0,0,0,0};
        for (int k0 = 0; k0 < 128; k0 += 32) {
            bf16x8 aH[2], aL[2];
#pragma unroll
            for (int i = 0; i < 2; i++) {
                int fa = (wave * 2 + i) * 16 + l15;
                int byte = fa * 256 + (swz(fa, (k0 >> 3) + quad) << 4);
                aH[i] = *(const bf16x8*)((const char*)GhL + byte);
                aL[i] = *(const bf16x8*)((const char*)GlL + byte);
            }
#pragma unroll
            for (int n = 0; n < 8; n++) {
                int gb = n * 16 + l15;
                bf16x8 bb = *(const bf16x8*)((const char*)SB + gb * 256 + (swz(gb, (k0 >> 3) + quad) << 4));
#pragma unroll
                for (int i = 0; i < 2; i++) {
                    acc[i][n] = __builtin_amdgcn_mfma_f32_16x16x32_bf16(aH[i], bb, acc[i][n], 0, 0, 0);
                    acc[i][n] = __builtin_amdgcn_mfma_f32_16x16x32_bf16(aL[i], bb, acc[i][n], 0, 0, 0);
                }
            }
        }
        float vsp[8];
#pragma unroll
        for (int n = 0; n < 8; n++) vsp[n] = 0.f;
#pragma unroll
        for (int i = 0; i < 2; i++)
#pragma unroll
            for (int n = 0; n < 8; n++) {
                int g = n * 16 + l15;
#pragma unroll
                for (int reg = 0; reg < 4; reg++) {
                    int f = (wave * 2 + i) * 16 + quad * 4 + reg;
                    float m1 = b2f(*(const unsigned short*)((const char*)SA + f * 256 + (swz(f, g >> 3) << 4) + (g & 7) * 2));
                    vsp[n] += m1 * acc[i][n][reg];
                }
            }
#pragma unroll
        for (int n = 0; n < 8; n++) {
            float v = vsp[n];
            v += __shfl_xor(v, 16, 64); v += __shfl_xor(v, 32, 64);
            if (lane < 16) scr_vs[wave * 128 + n * 16 + lane] = v;
        }
    }
    __syncthreads();
    // stats1 -> a1, b1
    if (tid < 128) {
        const int g = tid;
        float vs = scr_vs[g] + scr_vs[128 + g] + scr_vs[256 + g] + scr_vs[384 + g];
        float tg = 0.f;
        for (int fb = 0; fb < 16; fb++) {
            u16x8 h = *(const u16x8*)((const char*)SB + g * 256 + (swz(g, fb) << 4));
#pragma unroll
            for (int j = 0; j < 8; j++) tg += scr_s[fb * 8 + j] * b2f(h[j]);
        }
        float mean = tg * (1.f / LL);
        float var  = vs * (1.f / LL) - mean * mean;
        float a1 = gamma[g] * rsqrtf(var + EPSF);
        scr_a1[g] = a1;
        scr_b1[g] = beta[g] - mean * a1;
    }
    __syncthreads();
    // stage SB = [diag(a1)(I+W^T)]^T image: SB[g][h] = a1_h * (W[g][h] + (g==h))
#pragma unroll
    for (int i = 0; i < 16; i++) {
        int idx4 = (tid + i * 256) * 4;
        int g = idx4 >> 7, h0 = idx4 & 127;
        float4 w = *(const float4*)&ffw[g * FDIM + h0];
        float v0 = (w.x + ((g == h0 + 0) ? 1.f : 0.f)) * scr_a1[h0 + 0];
        float v1 = (w.y + ((g == h0 + 1) ? 1.f : 0.f)) * scr_a1[h0 + 1];
        float v2 = (w.z + ((g == h0 + 2) ? 1.f : 0.f)) * scr_a1[h0 + 2];
        float v3 = (w.w + ((g == h0 + 3) ? 1.f : 0.f)) * scr_a1[h0 + 3];
        ushort4 h; h.x = bfr(v0); h.y = bfr(v1); h.z = bfr(v2); h.w = bfr(v3);
        *(ushort4*)((char*)SB + g * 256 + (swz(g, h0 >> 3) << 4) + (h0 & 7) * 2) = h;
    }
    __syncthreads();
    // ---- M2 = M1 * diag(a1)(I+W^T)
    {
        f32x4 accM[2][8];
#pragma unroll
        for (int i = 0; i < 2; i++)
#pragma unroll
            for (int n = 0; n < 8; n++) accM[i][n] = (f32x4){0,0,0,0};
        for (int k0 = 0; k0 < 128; k0 += 32) {
            bf16x8 a[2];
#pragma unroll
            for (int i = 0; i < 2; i++) {
                int fa = (wave * 2 + i) * 16 + l15;
                a[i] = *(const bf16x8*)((const char*)SA + fa * 256 + (swz(fa, (k0 >> 3) + quad) << 4));
            }
#pragma unroll
            for (int n = 0; n < 8; n++) {
                int gb = n * 16 + l15;
                bf16x8 bb = *(const bf16x8*)((const char*)SB + gb * 256 + (swz(gb, (k0 >> 3) + quad) << 4));
#pragma unroll
                for (int i = 0; i < 2; i++)
                    accM[i][n] = __builtin_amdgcn_mfma_f32_16x16x32_bf16(a[i], bb, accM[i][n], 0, 0, 0);
            }
        }
        __syncthreads();           // all M1 reads done; overwrite SA with M2^T
#pragma unroll
        for (int i = 0; i < 2; i++)
#pragma unroll
            for (int n = 0; n < 8; n++) {
                int g = n * 16 + l15;
#pragma unroll
                for (int reg = 0; reg < 4; reg++) {
                    int f = (wave * 2 + i) * 16 + quad * 4 + reg;
                    *(unsigned short*)((char*)SA + g * 256 + (swz(g, f >> 3) << 4) + (f & 7) * 2) = bfr(accM[i][n][reg]);
                }
            }
    }
    __syncthreads();
    // ---- P2 = (Gh+Gl) * M2 ; varsum2_g = diag(M2^T G M2)
    {
        f32x4 acc[2][8];
#pragma unroll
        for (int i = 0; i < 2; i++)
#pragma unroll
            for (int n = 0; n < 8; n++) acc[i][n] = (f32x4){0,0,0,0};
        for (int k0 = 0; k0 < 128; k0 += 32) {
            bf16x8 aH[2], aL[2];
#pragma unroll
            for (int i = 0; i < 2; i++) {
                int fa = (wave * 2 + i) * 16 + l15;
                int byte = fa * 256 + (swz(fa, (k0 >> 3) + quad) << 4);
                aH[i] = *(const bf16x8*)((const char*)GhL + byte);
                aL[i] = *(const bf16x8*)((const char*)GlL + byte);
            }
#pragma unroll
            for (int n = 0; n < 8; n++) {
                int gb = n * 16 + l15;
                bf16x8 bb = *(const bf16x8*)((const char*)SA + gb * 256 + (swz(gb, (k0 >> 3) + quad) << 4));
#pragma unroll
                for (int i = 0; i < 2; i++) {
                    acc[i][n] = __builtin_amdgcn_mfma_f32_16x16x32_bf16(aH[i], bb, acc[i][n], 0, 0, 0);
                    acc[i][n] = __builtin_amdgcn_mfma_f32_16x16x32_bf16(aL[i], bb, acc[i][n], 0, 0, 0);
                }
            }
        }
        float vsp[8];
#pragma unroll
        for (int n = 0; n < 8; n++) vsp[n] = 0.f;
#pragma unroll
        for (int i = 0; i < 2; i++)
#pragma unroll
            for (int n = 0; n < 8; n++) {
                int g = n * 16 + l15;
#pragma unroll
                for (int reg = 0; reg < 4; reg++) {
                    int f = (wave * 2 + i) * 16 + quad * 4 + reg;
                    float m2 = b2f(*(const unsigned short*)((const char*)SA + g * 256 + (swz(g, f >> 3) << 4) + (f & 7) * 2));
                    vsp[n] += m2 * acc[i][n][reg];
                }
            }
#pragma unroll
        for (int n = 0; n < 8; n++) {
            float v = vsp[n];
            v += __shfl_xor(v, 16, 64); v += __shfl_xor(v, 32, 64);
            if (lane < 16) scr_vs[wave * 128 + n * 16 + lane] = v;
        }
    }
    __syncthreads();
    // stats2 -> a2, c'
    if (tid < 128) {
        const int g = tid;
        float vs = scr_vs[g] + scr_vs[128 + g] + scr_vs[256 + g] + scr_vs[384 + g];
        float t2 = 0.f;
        for (int fb = 0; fb < 16; fb++) {
            u16x8 h = *(const u16x8*)((const char*)SA + g * 256 + (swz(g, fb) << 4));
#pragma unroll
            for (int j = 0; j < 8; j++) t2 += scr_s[fb * 8 + j] * b2f(h[j]);
        }
        float c2 = ffb[g] + scr_b1[g];
        for (int hb = 0; hb < 32; hb++) {
            float4 w = *(const float4*)&ffw[g * FDIM + hb * 4];
            c2 += scr_b1[hb * 4 + 0] * w.x + scr_b1[hb * 4 + 1] * w.y
                + scr_b1[hb * 4 + 2] * w.z + scr_b1[hb * 4 + 3] * w.w;
        }
        float mean2 = t2 * (1.f / LL) + c2;
        float ey2   = vs * (1.f / LL) + 2.f * c2 * t2 * (1.f / LL) + c2 * c2;
        float var2  = ey2 - mean2 * mean2;
        float a2 = gamma[g] * rsqrtf(var2 + EPSF);
        scr_a2[g] = a2;
        ws[OFF_CP + b * FDIM + g] = a2 * (c2 - mean2) + beta[g];
    }
    __syncthreads();
    // M'^T = a2-scaled M2^T -> global MP (same swizzled byte image as LDS)
    {
        unsigned short* MP = (unsigned short*)(ws + OFF_MP) + (size_t)b * 16384;
        const int g = tid >> 1, half = (tid & 1) * 8;
        float a2 = scr_a2[g];
        for (int s = 0; s < 8; s++) {
            int slot = half + s;
            u16x8 h = *(const u16x8*)((const char*)SA + g * 256 + slot * 16);
#pragma unroll
            for (int j = 0; j < 8; j++) h[j] = bfr(b2f(h[j]) * a2);
            *(u16x8*)&MP[g * 128 + slot * 8] = h;
        }
    }
}

// ---------------------------------------------------------------- out = X * M' + c'
// grid (64, 32), 256 threads, 64-row tiles; X fp32 (L3-hot), M' via LDS DMA.
__global__ __launch_bounds__(256) void outgemm_kernel(const float* __restrict__ x,
                                                      const float* __restrict__ ws,
                                                      float* __restrict__ out) {
    __shared__ __align__(16) unsigned short Xs[64][136];
    __shared__ __align__(16) unsigned short Bs[16384];
    __shared__ float cps[128];
    const int b = blockIdx.y, r0 = blockIdx.x * 64, tid = threadIdx.x;
    const char* mp = (const char*)ws + (size_t)OFF_MP * 4 + (size_t)b * 32768;
#pragma unroll
    for (int i = 0; i < 8; i++)
        ldsload16((char*)Bs + i * 4096 + tid * 16, mp + i * 4096 + tid * 16);
    const float* Xg = x + (size_t)b * LL * FDIM + (size_t)r0 * FDIM;
#pragma unroll
    for (int i = 0; i < 8; i++) {
        int idx4 = (tid + i * 256) * 4;
        int r = idx4 >> 7, c = idx4 & 127;
        float4 v = *(const float4*)&Xg[r * FDIM + c];
        ushort4 h; h.x = bfr(v.x); h.y = bfr(v.y); h.z = bfr(v.z); h.w = bfr(v.w);
        *(ushort4*)&Xs[r][c] = h;
    }
    if (tid < 128) cps[tid] = ws[OFF_CP + b * FDIM + tid];
    __syncthreads();
    const int wave = tid >> 6, lane = tid & 63, l15 = lane & 15, quad = lane >> 4;
    const int rowA = wave * 16 + l15;
    f32x4 acc[8];
#pragma unroll
    for (int t = 0; t < 8; t++) acc[t] = (f32x4){0,0,0,0};
#pragma unroll
    for (int k0 = 0; k0 < 128; k0 += 32) {
        bf16x8 a = *(const bf16x8*)&Xs[rowA][k0 + quad * 8];
#pragma unroll
        for (int t = 0; t < 8; t++) {
            int gb = t * 16 + l15;
            bf16x8 bb = *(const bf16x8*)((const char*)Bs + gb * 256 + (swz(gb, (k0 >> 3) + quad) << 4));
            acc[t] = __builtin_amdgcn_mfma_f32_16x16x32_bf16(a, bb, acc[t], 0, 0, 0);
        }
    }
    float* Ob = out + ((size_t)b * LL + r0) * FDIM;
#pragma unroll
    for (int t = 0; t < 8; t++) {
        int col = t * 16 + l15;
        float cp = cps[col];
#pragma unroll
        for (int reg = 0; reg < 4; reg++)
            Ob[(wave * 16 + quad * 4 + reg) * FDIM + col] = acc[t][reg] + cp;
    }
}

extern "C" void kernel_launch(void* const* d_in, const int* in_sizes, int n_in,
                              void* d_out, int out_size, void* d_ws, size_t ws_size,
                              hipStream_t stream) {
    const float* x     = (const float*)d_in[0];
    const float* q_w   = (const float*)d_in[1];
    const float* q_b   = (const float*)d_in[2];
    const float* k_w   = (const float*)d_in[3];
    const float* k_b   = (const float*)d_in[4];
    const float* ff_w  = (const float*)d_in[5];
    const float* ff_b  = (const float*)d_in[6];
    const float* gamma = (const float*)d_in[7];
    const float* beta  = (const float*)d_in[8];
    float* out = (float*)d_out;
    float* ws  = (float*)d_ws;

    hipMemsetAsync(ws, 0, 12288 * sizeof(float), stream);   // qsum,ksum,ssum only
    pass1_kernel<<<dim3(16, 32), 256, 0, stream>>>(x, q_w, k_w, ws);
    reduce_kernel<<<512, 256, 0, stream>>>(ws);
    solve_kernel<<<32, 256, 0, stream>>>(q_w, q_b, k_w, k_b, ff_w, ff_b, gamma, beta, ws);
    outgemm_kernel<<<dim3(64, 32), 256, 0, stream>>>(x, ws, out);
}

// Round 6
// 181.981 us; speedup vs baseline: 1.2127x; 1.0056x over previous
//
#include <hip/hip_runtime.h>
#include <math.h>

typedef __attribute__((ext_vector_type(8))) short bf16x8;
typedef __attribute__((ext_vector_type(8))) unsigned short u16x8;
typedef __attribute__((ext_vector_type(4))) float f32x4;

#define LL    4096
#define FDIM  128
#define NLEV  12
#define EPSF  1e-5f
#define SCL   0.08838834764831845f   // 1/sqrt(128)

// ---------------- ws layout (float offsets) ----------------
#define OFF_QP   0          // colsum partials: [3][16][32][128] = 196608
#define OFF_QSUM 196608     // reduced colsums: [3][32][128] = 12288 (q,k,s)
#define OFF_CP   208896     // 32*128 fp32 c'
#define OFF_MP   212992     // bf16 M'^T swizzled image: 32*16384 ushort = 262144 float slots
#define OFF_GH   475136     // bf16 Gh swizzled image: 262144 float slots
#define OFF_GL   737280     // bf16 Gl swizzled image: 262144 float slots
#define OFF_GP   999424     // fp32 Gram partials: 16 chunks * 524288 = 8388608

__device__ __forceinline__ unsigned short bfr(float f) {   // fp32 -> bf16 RTNE
    union { float f; unsigned u; } v; v.f = f;
    unsigned r = v.u + 0x7FFF + ((v.u >> 16) & 1);
    return (unsigned short)(r >> 16);
}
__device__ __forceinline__ float b2f(unsigned short u) {
    union { float f; unsigned u; } v; v.u = ((unsigned)u) << 16; return v.f;
}
// XOR swizzle of 16B slots within a row.
__device__ __forceinline__ int swz(int row, int kblk) {
    return kblk ^ (row & 7) ^ ((row >> 3) & 7);
}
__device__ __forceinline__ void ldsload16(void* lds, const void* g) {
    __builtin_amdgcn_global_load_lds((const __attribute__((address_space(1))) unsigned int*)g,
                                     (__attribute__((address_space(3))) unsigned int*)lds, 16, 0, 0);
}

// ---------------------------------------------------------------- pass1
// grid (16, 32), 256 threads: 256-row chunk per block, two 128-row stages
// through one 32KB LDS buffer. Streams colsum partials + Gram partial (no atomics).
__global__ __launch_bounds__(256) void pass1_kernel(const float* __restrict__ x,
                                                    const float* __restrict__ qw,
                                                    const float* __restrict__ kw,
                                                    float* __restrict__ ws) {
    __shared__ __align__(16) unsigned short XT[16384];   // 32KB: [f][k0..127] bf16, slot-swizzled
    __shared__ float cq[256], ck[256];
    const int b = blockIdx.y, cch = blockIdx.x, c0 = cch * 256;
    const int tid = threadIdx.x;
    {   // per-row wavelet coefficients (fused coeff_kernel)
        int row = c0 + tid;
        float pq = 1.f, pk = 1.f;
#pragma unroll
        for (int i = 0; i < NLEV; i++) {
            int bit = (row >> i) & 1;
            pq *= qw[2 * i + bit];
            pk *= kw[2 * i + bit];
        }
        cq[tid] = pq; ck[tid] = pk;
    }
    __syncthreads();
    const int f0 = (tid & 31) * 4;
    const int rh = tid >> 5;                    // 0..7
    const int wave = tid >> 6, lane = tid & 63, l15 = lane & 15, quad = lane >> 4;
    f32x4 aq = {0,0,0,0}, ak = {0,0,0,0}, asv = {0,0,0,0};
    f32x4 acc[2][8];
#pragma unroll
    for (int i = 0; i < 2; i++)
#pragma unroll
        for (int n = 0; n < 8; n++) acc[i][n] = (f32x4){0,0,0,0};

    for (int stage = 0; stage < 2; stage++) {
        const float* Xg = x + ((size_t)b * LL + c0 + stage * 128) * FDIM;
#pragma unroll
        for (int g = 0; g < 2; g++) {
            const int lb = g * 64 + rh * 8;     // 8 consecutive rows per thread
            float4 v[8];
#pragma unroll
            for (int s = 0; s < 8; s++) v[s] = *(const float4*)&Xg[(size_t)(lb + s) * FDIM + f0];
            u16x8 hj[4];                        // transpose-pack: hj[j][s] = bf16(X[lb+s][f0+j])
#pragma unroll
            for (int s = 0; s < 8; s++) {
                int ci = stage * 128 + lb + s;
                float wq = cq[ci], wk = ck[ci];
                aq[0] += wq * v[s].x; aq[1] += wq * v[s].y; aq[2] += wq * v[s].z; aq[3] += wq * v[s].w;
                ak[0] += wk * v[s].x; ak[1] += wk * v[s].y; ak[2] += wk * v[s].z; ak[3] += wk * v[s].w;
                asv[0] += v[s].x; asv[1] += v[s].y; asv[2] += v[s].z; asv[3] += v[s].w;
                hj[0][s] = bfr(v[s].x); hj[1][s] = bfr(v[s].y);
                hj[2][s] = bfr(v[s].z); hj[3][s] = bfr(v[s].w);
            }
#pragma unroll
            for (int j = 0; j < 4; j++) {       // b128 write: 8 l's of row f0+j
                int f = f0 + j;
                *(u16x8*)((char*)XT + f * 256 + (swz(f, g * 8 + rh) << 4)) = hj[j];
            }
        }
        __syncthreads();
        // Gram accumulate over this stage's K=128 (4 phases)
#pragma unroll
        for (int k0 = 0; k0 < 128; k0 += 32) {
            bf16x8 a[2];
#pragma unroll
            for (int i = 0; i < 2; i++) {
                int fa = (wave * 2 + i) * 16 + l15;
                a[i] = *(const bf16x8*)((const char*)XT + fa * 256 + (swz(fa, (k0 >> 3) + quad) << 4));
            }
#pragma unroll
            for (int n = 0; n < 8; n++) {
                int gb = n * 16 + l15;
                bf16x8 bb = *(const bf16x8*)((const char*)XT + gb * 256 + (swz(gb, (k0 >> 3) + quad) << 4));
                acc[0][n] = __builtin_amdgcn_mfma_f32_16x16x32_bf16(a[0], bb, acc[0][n], 0, 0, 0);
                acc[1][n] = __builtin_amdgcn_mfma_f32_16x16x32_bf16(a[1], bb, acc[1][n], 0, 0, 0);
            }
        }
        __syncthreads();
    }
    // streaming Gram partial store (16 chunks/batch, no contention)
    float* Gp = ws + OFF_GP + ((size_t)cch * 32 + b) * 16384;
#pragma unroll
    for (int i = 0; i < 2; i++)
#pragma unroll
        for (int n = 0; n < 8; n++) {
            int g = n * 16 + l15;
#pragma unroll
            for (int reg = 0; reg < 4; reg++) {
                int f = (wave * 2 + i) * 16 + quad * 4 + reg;
                Gp[f * 128 + g] = acc[i][n][reg];
            }
        }
    // colsum partials (streamed, no atomics), reusing XT as float scratch [3][8][132]
    float* red = (float*)XT;
    *(f32x4*)&red[0 * 1056 + rh * 132 + f0] = aq;
    *(f32x4*)&red[1 * 1056 + rh * 132 + f0] = ak;
    *(f32x4*)&red[2 * 1056 + rh * 132 + f0] = asv;
    __syncthreads();
    if (tid < 128) {
#pragma unroll
        for (int p = 0; p < 3; p++) {
            float s = 0.f;
#pragma unroll
            for (int r = 0; r < 8; r++) s += red[p * 1056 + r * 132 + tid];
            ws[OFF_QP + (size_t)p * 65536 + (size_t)cch * 4096 + b * 128 + tid] = s;
        }
    }
}

// ---------------------------------------------------------------- reduce
// grid 512, 256 threads. 16 Gram partials -> split-bf16 Gh/Gl swizzled images;
// blocks 0..11 also reduce the colsum partials.
__global__ __launch_bounds__(256) void reduce_kernel(float* __restrict__ ws) {
    const int tid = threadIdx.x;
    const size_t c0 = (size_t)blockIdx.x * 1024 + tid * 4;
    const float* Gp = ws + OFF_GP;
    f32x4 s = {0.f, 0.f, 0.f, 0.f};
#pragma unroll
    for (int ch = 0; ch < 16; ch++) {
        float4 u = *(const float4*)&Gp[(size_t)ch * 524288 + c0];
        s[0] += u.x; s[1] += u.y; s[2] += u.z; s[3] += u.w;
    }
    ushort4 gh, gl;
    gh.x = bfr(s[0]); gl.x = bfr(s[0] - b2f(gh.x));
    gh.y = bfr(s[1]); gl.y = bfr(s[1] - b2f(gh.y));
    gh.z = bfr(s[2]); gl.z = bfr(s[2] - b2f(gh.z));
    gh.w = bfr(s[3]); gl.w = bfr(s[3] - b2f(gh.w));
    const int bb = (int)(c0 >> 14), cell = (int)(c0 & 16383);
    const int a = cell >> 7, k0 = cell & 127;
    const size_t uidx = (size_t)bb * 16384 + a * 128 + (swz(a, k0 >> 3) << 3) + (k0 & 7);
    *(ushort4*)((unsigned short*)(ws + OFF_GH) + uidx) = gh;
    *(ushort4*)((unsigned short*)(ws + OFF_GL) + uidx) = gl;
    if (blockIdx.x < 12) {
        int o0 = blockIdx.x * 1024 + tid * 4;   // 0..12287
        int p = o0 >> 12, rem = o0 & 4095;
        const float* src = ws + OFF_QP + (size_t)p * 65536 + rem;
        f32x4 t = {0.f, 0.f, 0.f, 0.f};
#pragma unroll
        for (int ch = 0; ch < 16; ch++) {
            float4 u = *(const float4*)&src[ch * 4096];
            t[0] += u.x; t[1] += u.y; t[2] += u.z; t[3] += u.w;
        }
        *(f32x4*)&ws[OFF_QSUM + o0] = t;
    }
}

// ---------------------------------------------------------------- solve: per-batch fold to M', c'
// grid 32, 256 threads. Gh/Gl staged via global_load_lds DMA (pre-swizzled images).
__global__ __launch_bounds__(256) void solve_kernel(const float* __restrict__ qw,
                                                    const float* __restrict__ qb,
                                                    const float* __restrict__ kw,
                                                    const float* __restrict__ kb,
                                                    const float* __restrict__ ffw,
                                                    const float* __restrict__ ffb,
                                                    const float* __restrict__ gamma,
                                                    const float* __restrict__ beta,
                                                    float* __restrict__ ws) {
    __shared__ __align__(16) unsigned short GhL[16384];
    __shared__ __align__(16) unsigned short GlL[16384];
    __shared__ __align__(16) unsigned short SA[16384];   // M1 row-major; later M2^T
    __shared__ __align__(16) unsigned short SB[16384];   // M1^T; later diag(a1)(I+W^T) image
    __shared__ float scr_k[128], scr_s[128], scr_a1[128], scr_b1[128], scr_a2[128];
    __shared__ float scr_vs[512];
    __shared__ float scr_mm[4];
    const int b = blockIdx.x, tid = threadIdx.x;
    const int wave = tid >> 6, lane = tid & 63, l15 = lane & 15, quad = lane >> 4;

    {   // stage Gh/Gl (pre-swizzled images) via DMA
        const char* gh = (const char*)ws + (size_t)OFF_GH * 4 + (size_t)b * 32768;
        const char* gl = (const char*)ws + (size_t)OFF_GL * 4 + (size_t)b * 32768;
#pragma unroll
        for (int i = 0; i < 8; i++) {
            ldsload16((char*)GhL + i * 4096 + tid * 16, gh + i * 4096 + tid * 16);
            ldsload16((char*)GlL + i * 4096 + tid * 16, gl + i * 4096 + tid * 16);
        }
    }
    // dq/dk (uniform recurrence)
    float dq = 0.f, dk = 0.f;
#pragma unroll
    for (int i = 0; i < NLEV; i++) {
        dq = (qw[2 * i] + qw[2 * i + 1]) * dq + qb[i];
        dk = (kw[2 * i] + kw[2 * i + 1]) * dk + kb[i];
    }
    float qf = 0.f, kf = 0.f;
    if (tid < 128) {
        qf = (ws[OFF_QSUM + b * FDIM + tid] + dq) * SCL;
        kf = ws[OFF_QSUM + 4096 + b * FDIM + tid] + dk;
        scr_k[tid] = kf;
        scr_s[tid] = ws[OFF_QSUM + 8192 + b * FDIM + tid];
        float mx = kf, mn = kf;
#pragma unroll
        for (int off = 32; off; off >>= 1) {
            mx = fmaxf(mx, __shfl_xor(mx, off, 64));
            mn = fminf(mn, __shfl_xor(mn, off, 64));
        }
        if (lane == 0) { scr_mm[wave * 2] = mx; scr_mm[wave * 2 + 1] = mn; }
    }
    __syncthreads();
    float kmax = fmaxf(scr_mm[0], scr_mm[2]);
    float kmin = fminf(scr_mm[1], scr_mm[3]);

    // att: rank-1 scores -> softmax rows, fold +I; SA = M1 row-major, SB = M1^T
    if (tid < 128) {
        const int f = tid;
        float m = (qf >= 0.f) ? qf * kmax : qf * kmin;
        float ssum = 0.f;
        for (int gi = 0; gi < 16; gi++) {
            u16x8 h;
#pragma unroll
            for (int j = 0; j < 8; j++) {
                float e = __expf(qf * scr_k[gi * 8 + j] - m);
                ssum += e;
                h[j] = bfr(e);
            }
            *(u16x8*)((char*)SA + f * 256 + (swz(f, gi) << 4)) = h;
        }
        float sinv = 1.f / ssum;
        for (int gi = 0; gi < 16; gi++) {
            char* pa = (char*)SA + f * 256 + (swz(f, gi) << 4);
            u16x8 h = *(u16x8*)pa;
#pragma unroll
            for (int j = 0; j < 8; j++) {
                int g = gi * 8 + j;
                float v = b2f(h[j]) * sinv;
                if (g == f) v += 1.f;
                unsigned short u = bfr(v);
                h[j] = u;
                *(unsigned short*)((char*)SB + g * 256 + (swz(g, f >> 3) << 4) + (f & 7) * 2) = u;
            }
            *(u16x8*)pa = h;
        }
    }
    __syncthreads();

    // ---- P1 = (Gh+Gl) * M1 ; varsum1_g = diag(M1^T G M1)
    {
        f32x4 acc[2][8];
#pragma unroll
        for (int i = 0; i < 2; i++)
#pragma unroll
            for (int n = 0; n < 8; n++) acc[i][n] = (f32x4){0,0,0,0};
        for (int k0 = 0; k0 < 128; k0 += 32) {
            bf16x8 aH[2], aL[2];
#pragma unroll
            for (int i = 0; i < 2; i++) {
                int fa = (wave * 2 + i) * 16 + l15;
                int byte = fa * 256 + (swz(fa, (k0 >> 3) + quad) << 4);
                aH[i] = *(const bf16x8*)((const char*)GhL + byte);
                aL[i] = *(const bf16x8*)((const char*)GlL + byte);
            }
#pragma unroll
            for (int n = 0; n < 8; n++) {
                int gb = n * 16 + l15;
                bf16x8 bb = *(const bf16x8*)((const char*)SB + gb * 256 + (swz(gb, (k0 >> 3) + quad) << 4));
#pragma unroll
                for (int i = 0; i < 2; i++) {
                    acc[i][n] = __builtin_amdgcn_mfma_f32_16x16x32_bf16(aH[i], bb, acc[i][n], 0, 0, 0);
                    acc[i][n] = __builtin_amdgcn_mfma_f32_16x16x32_bf16(aL[i], bb, acc[i][n], 0, 0, 0);
                }
            }
        }
        float vsp[8];
#pragma unroll
        for (int n = 0; n < 8; n++) vsp[n] = 0.f;
#pragma unroll
        for (int i = 0; i < 2; i++)
#pragma unroll
            for (int n = 0; n < 8; n++) {
                int g = n * 16 + l15;
#pragma unroll
                for (int reg = 0; reg < 4; reg++) {
                    int f = (wave * 2 + i) * 16 + quad * 4 + reg;
                    float m1 = b2f(*(const unsigned short*)((const char*)SA + f * 256 + (swz(f, g >> 3) << 4) + (g & 7) * 2));
                    vsp[n] += m1 * acc[i][n][reg];
                }
            }
#pragma unroll
        for (int n = 0; n < 8; n++) {
            float v = vsp[n];
            v += __shfl_xor(v, 16, 64); v += __shfl_xor(v, 32, 64);
            if (lane < 16) scr_vs[wave * 128 + n * 16 + lane] = v;
        }
    }
    __syncthreads();
    // stats1 -> a1, b1
    if (tid < 128) {
        const int g = tid;
        float vs = scr_vs[g] + scr_vs[128 + g] + scr_vs[256 + g] + scr_vs[384 + g];
        float tg = 0.f;
        for (int fb = 0; fb < 16; fb++) {
            u16x8 h = *(const u16x8*)((const char*)SB + g * 256 + (swz(g, fb) << 4));
#pragma unroll
            for (int j = 0; j < 8; j++) tg += scr_s[fb * 8 + j] * b2f(h[j]);
        }
        float mean = tg * (1.f / LL);
        float var  = vs * (1.f / LL) - mean * mean;
        float a1 = gamma[g] * rsqrtf(var + EPSF);
        scr_a1[g] = a1;
        scr_b1[g] = beta[g] - mean * a1;
    }
    __syncthreads();
    // stage SB = [diag(a1)(I+W^T)]^T image: SB[g][h] = a1_h * (W[g][h] + (g==h))
#pragma unroll
    for (int i = 0; i < 16; i++) {
        int idx4 = (tid + i * 256) * 4;
        int g = idx4 >> 7, h0 = idx4 & 127;
        float4 w = *(const float4*)&ffw[g * FDIM + h0];
        float v0 = (w.x + ((g == h0 + 0) ? 1.f : 0.f)) * scr_a1[h0 + 0];
        float v1 = (w.y + ((g == h0 + 1) ? 1.f : 0.f)) * scr_a1[h0 + 1];
        float v2 = (w.z + ((g == h0 + 2) ? 1.f : 0.f)) * scr_a1[h0 + 2];
        float v3 = (w.w + ((g == h0 + 3) ? 1.f : 0.f)) * scr_a1[h0 + 3];
        ushort4 h; h.x = bfr(v0); h.y = bfr(v1); h.z = bfr(v2); h.w = bfr(v3);
        *(ushort4*)((char*)SB + g * 256 + (swz(g, h0 >> 3) << 4) + (h0 & 7) * 2) = h;
    }
    __syncthreads();
    // ---- M2 = M1 * diag(a1)(I+W^T)
    {
        f32x4 accM[2][8];
#pragma unroll
        for (int i = 0; i < 2; i++)
#pragma unroll
            for (int n = 0; n < 8; n++) accM[i][n] = (f32x4){0,0,0,0};
        for (int k0 = 0; k0 < 128; k0 += 32) {
            bf16x8 a[2];
#pragma unroll
            for (int i = 0; i < 2; i++) {
                int fa = (wave * 2 + i) * 16 + l15;
                a[i] = *(const bf16x8*)((const char*)SA + fa * 256 + (swz(fa, (k0 >> 3) + quad) << 4));
            }
#pragma unroll
            for (int n = 0; n < 8; n++) {
                int gb = n * 16 + l15;
                bf16x8 bb = *(const bf16x8*)((const char*)SB + gb * 256 + (swz(gb, (k0 >> 3) + quad) << 4));
#pragma unroll
                for (int i = 0; i < 2; i++)
                    accM[i][n] = __builtin_amdgcn_mfma_f32_16x16x32_bf16(a[i], bb, accM[i][n], 0, 0, 0);
            }
        }
        __syncthreads();           // all M1 reads done; overwrite SA with M2^T
#pragma unroll
        for (int i = 0; i < 2; i++)
#pragma unroll
            for (int n = 0; n < 8; n++) {
                int g = n * 16 + l15;
#pragma unroll
                for (int reg = 0; reg < 4; reg++) {
                    int f = (wave * 2 + i) * 16 + quad * 4 + reg;
                    *(unsigned short*)((char*)SA + g * 256 + (swz(g, f >> 3) << 4) + (f & 7) * 2) = bfr(accM[i][n][reg]);
                }
            }
    }
    __syncthreads();
    // ---- P2 = (Gh+Gl) * M2 ; varsum2_g = diag(M2^T G M2)
    {
        f32x4 acc[2][8];
#pragma unroll
        for (int i = 0; i < 2; i++)
#pragma unroll
            for (int n = 0; n < 8; n++) acc[i][n] = (f32x4){0,0,0,0};
        for (int k0 = 0; k0 < 128; k0 += 32) {
            bf16x8 aH[2], aL[2];
#pragma unroll
            for (int i = 0; i < 2; i++) {
                int fa = (wave * 2 + i) * 16 + l15;
                int byte = fa * 256 + (swz(fa, (k0 >> 3) + quad) << 4);
                aH[i] = *(const bf16x8*)((const char*)GhL + byte);
                aL[i] = *(const bf16x8*)((const char*)GlL + byte);
            }
#pragma unroll
            for (int n = 0; n < 8; n++) {
                int gb = n * 16 + l15;
                bf16x8 bb = *(const bf16x8*)((const char*)SA + gb * 256 + (swz(gb, (k0 >> 3) + quad) << 4));
#pragma unroll
                for (int i = 0; i < 2; i++) {
                    acc[i][n] = __builtin_amdgcn_mfma_f32_16x16x32_bf16(aH[i], bb, acc[i][n], 0, 0, 0);
                    acc[i][n] = __builtin_amdgcn_mfma_f32_16x16x32_bf16(aL[i], bb, acc[i][n], 0, 0, 0);
                }
            }
        }
        float vsp[8];
#pragma unroll
        for (int n = 0; n < 8; n++) vsp[n] = 0.f;
#pragma unroll
        for (int i = 0; i < 2; i++)
#pragma unroll
            for (int n = 0; n < 8; n++) {
                int g = n * 16 + l15;
#pragma unroll
                for (int reg = 0; reg < 4; reg++) {
                    int f = (wave * 2 + i) * 16 + quad * 4 + reg;
                    float m2 = b2f(*(const unsigned short*)((const char*)SA + g * 256 + (swz(g, f >> 3) << 4) + (f & 7) * 2));
                    vsp[n] += m2 * acc[i][n][reg];
                }
            }
#pragma unroll
        for (int n = 0; n < 8; n++) {
            float v = vsp[n];
            v += __shfl_xor(v, 16, 64); v += __shfl_xor(v, 32, 64);
            if (lane < 16) scr_vs[wave * 128 + n * 16 + lane] = v;
        }
    }
    __syncthreads();
    // stats2 -> a2, c'
    if (tid < 128) {
        const int g = tid;
        float vs = scr_vs[g] + scr_vs[128 + g] + scr_vs[256 + g] + scr_vs[384 + g];
        float t2 = 0.f;
        for (int fb = 0; fb < 16; fb++) {
            u16x8 h = *(const u16x8*)((const char*)SA + g * 256 + (swz(g, fb) << 4));
#pragma unroll
            for (int j = 0; j < 8; j++) t2 += scr_s[fb * 8 + j] * b2f(h[j]);
        }
        float c2 = ffb[g] + scr_b1[g];
        for (int hb = 0; hb < 32; hb++) {
            float4 w = *(const float4*)&ffw[g * FDIM + hb * 4];
            c2 += scr_b1[hb * 4 + 0] * w.x + scr_b1[hb * 4 + 1] * w.y
                + scr_b1[hb * 4 + 2] * w.z + scr_b1[hb * 4 + 3] * w.w;
        }
        float mean2 = t2 * (1.f / LL) + c2;
        float ey2   = vs * (1.f / LL) + 2.f * c2 * t2 * (1.f / LL) + c2 * c2;
        float var2  = ey2 - mean2 * mean2;
        float a2 = gamma[g] * rsqrtf(var2 + EPSF);
        scr_a2[g] = a2;
        ws[OFF_CP + b * FDIM + g] = a2 * (c2 - mean2) + beta[g];
    }
    __syncthreads();
    // M'^T = a2-scaled M2^T -> global MP (same swizzled byte image as LDS)
    {
        unsigned short* MP = (unsigned short*)(ws + OFF_MP) + (size_t)b * 16384;
        const int g = tid >> 1, half = (tid & 1) * 8;
        float a2 = scr_a2[g];
        for (int s = 0; s < 8; s++) {
            int slot = half + s;
            u16x8 h = *(const u16x8*)((const char*)SA + g * 256 + slot * 16);
#pragma unroll
            for (int j = 0; j < 8; j++) h[j] = bfr(b2f(h[j]) * a2);
            *(u16x8*)&MP[g * 128 + slot * 8] = h;
        }
    }
}

// ---------------------------------------------------------------- out = X * M' + c'
// grid (64, 32), 256 threads, 64-row tiles; X fp32 (L3-hot), M' via LDS DMA.
__global__ __launch_bounds__(256) void outgemm_kernel(const float* __restrict__ x,
                                                      const float* __restrict__ ws,
                                                      float* __restrict__ out) {
    __shared__ __align__(16) unsigned short Xs[64][136];
    __shared__ __align__(16) unsigned short Bs[16384];
    __shared__ float cps[128];
    const int b = blockIdx.y, r0 = blockIdx.x * 64, tid = threadIdx.x;
    const char* mp = (const char*)ws + (size_t)OFF_MP * 4 + (size_t)b * 32768;
#pragma unroll
    for (int i = 0; i < 8; i++)
        ldsload16((char*)Bs + i * 4096 + tid * 16, mp + i * 4096 + tid * 16);
    const float* Xg = x + (size_t)b * LL * FDIM + (size_t)r0 * FDIM;
#pragma unroll
    for (int i = 0; i < 8; i++) {
        int idx4 = (tid + i * 256) * 4;
        int r = idx4 >> 7, c = idx4 & 127;
        float4 v = *(const float4*)&Xg[r * FDIM + c];
        ushort4 h; h.x = bfr(v.x); h.y = bfr(v.y); h.z = bfr(v.z); h.w = bfr(v.w);
        *(ushort4*)&Xs[r][c] = h;
    }
    if (tid < 128) cps[tid] = ws[OFF_CP + b * FDIM + tid];
    __syncthreads();
    const int wave = tid >> 6, lane = tid & 63, l15 = lane & 15, quad = lane >> 4;
    const int rowA = wave * 16 + l15;
    f32x4 acc[8];
#pragma unroll
    for (int t = 0; t < 8; t++) acc[t] = (f32x4){0,0,0,0};
#pragma unroll
    for (int k0 = 0; k0 < 128; k0 += 32) {
        bf16x8 a = *(const bf16x8*)&Xs[rowA][k0 + quad * 8];
#pragma unroll
        for (int t = 0; t < 8; t++) {
            int gb = t * 16 + l15;
            bf16x8 bb = *(const bf16x8*)((const char*)Bs + gb * 256 + (swz(gb, (k0 >> 3) + quad) << 4));
            acc[t] = __builtin_amdgcn_mfma_f32_16x16x32_bf16(a, bb, acc[t], 0, 0, 0);
        }
    }
    float* Ob = out + ((size_t)b * LL + r0) * FDIM;
#pragma unroll
    for (int t = 0; t < 8; t++) {
        int col = t * 16 + l15;
        float cp = cps[col];
#pragma unroll
        for (int reg = 0; reg < 4; reg++)
            Ob[(wave * 16 + quad * 4 + reg) * FDIM + col] = acc[t][reg] + cp;
    }
}

extern "C" void kernel_launch(void* const* d_in, const int* in_sizes, int n_in,
                              void* d_out, int out_size, void* d_ws, size_t ws_size,
                              hipStream_t stream) {
    const float* x     = (const float*)d_in[0];
    const float* q_w   = (const float*)d_in[1];
    const float* q_b   = (const float*)d_in[2];
    const float* k_w   = (const float*)d_in[3];
    const float* k_b   = (const float*)d_in[4];
    const float* ff_w  = (const float*)d_in[5];
    const float* ff_b  = (const float*)d_in[6];
    const float* gamma = (const float*)d_in[7];
    const float* beta  = (const float*)d_in[8];
    float* out = (float*)d_out;
    float* ws  = (float*)d_ws;

    pass1_kernel<<<dim3(16, 32), 256, 0, stream>>>(x, q_w, k_w, ws);
    reduce_kernel<<<512, 256, 0, stream>>>(ws);
    solve_kernel<<<32, 256, 0, stream>>>(q_w, q_b, k_w, k_b, ff_w, ff_b, gamma, beta, ws);
    outgemm_kernel<<<dim3(64, 32), 256, 0, stream>>>(x, ws, out);
}

// Round 7
// 177.048 us; speedup vs baseline: 1.2465x; 1.0279x over previous
//
#include <hip/hip_runtime.h>
#include <math.h>

typedef __attribute__((ext_vector_type(8))) short bf16x8;
typedef __attribute__((ext_vector_type(8))) unsigned short u16x8;
typedef __attribute__((ext_vector_type(4))) float f32x4;

#define LL    4096
#define FDIM  128
#define NLEV  12
#define EPSF  1e-5f
#define SCL   0.08838834764831845f   // 1/sqrt(128)

// ---------------- ws layout (float offsets) ----------------
#define OFF_QP   0          // colsum partials: [3][16][32][128] = 196608
#define OFF_QSUM 196608     // reduced colsums: [3][32][128] = 12288 (q,k,s)
#define OFF_CP   208896     // 32*128 fp32 c'
#define OFF_MP   212992     // bf16 M'^T swizzled image: 32*16384 ushort = 262144 float slots
#define OFF_GH   475136     // bf16 Gh swizzled image: 262144 float slots
#define OFF_GL   737280     // bf16 Gl swizzled image: 262144 float slots
#define OFF_GP   999424     // fp32 Gram partials: 16 chunks * 524288 = 8388608

__device__ __forceinline__ unsigned short bfr(float f) {   // fp32 -> bf16 RTNE
    union { float f; unsigned u; } v; v.f = f;
    unsigned r = v.u + 0x7FFF + ((v.u >> 16) & 1);
    return (unsigned short)(r >> 16);
}
__device__ __forceinline__ float b2f(unsigned short u) {
    union { float f; unsigned u; } v; v.u = ((unsigned)u) << 16; return v.f;
}
// XOR swizzle of 16B slots within a row.
__device__ __forceinline__ int swz(int row, int kblk) {
    return kblk ^ (row & 7) ^ ((row >> 3) & 7);
}
__device__ __forceinline__ void ldsload16(void* lds, const void* g) {
    __builtin_amdgcn_global_load_lds((const __attribute__((address_space(1))) unsigned int*)g,
                                     (__attribute__((address_space(3))) unsigned int*)lds, 16, 0, 0);
}

// ---------------------------------------------------------------- pass1 (unchanged from r6)
// grid (16, 32), 256 threads: 256-row chunk per block, two 128-row stages
// through one 32KB LDS buffer. Streams colsum partials + Gram partial (no atomics).
__global__ __launch_bounds__(256) void pass1_kernel(const float* __restrict__ x,
                                                    const float* __restrict__ qw,
                                                    const float* __restrict__ kw,
                                                    float* __restrict__ ws) {
    __shared__ __align__(16) unsigned short XT[16384];   // 32KB: [f][k0..127] bf16, slot-swizzled
    __shared__ float cq[256], ck[256];
    const int b = blockIdx.y, cch = blockIdx.x, c0 = cch * 256;
    const int tid = threadIdx.x;
    {   // per-row wavelet coefficients (fused coeff_kernel)
        int row = c0 + tid;
        float pq = 1.f, pk = 1.f;
#pragma unroll
        for (int i = 0; i < NLEV; i++) {
            int bit = (row >> i) & 1;
            pq *= qw[2 * i + bit];
            pk *= kw[2 * i + bit];
        }
        cq[tid] = pq; ck[tid] = pk;
    }
    __syncthreads();
    const int f0 = (tid & 31) * 4;
    const int rh = tid >> 5;                    // 0..7
    const int wave = tid >> 6, lane = tid & 63, l15 = lane & 15, quad = lane >> 4;
    f32x4 aq = {0,0,0,0}, ak = {0,0,0,0}, asv = {0,0,0,0};
    f32x4 acc[2][8];
#pragma unroll
    for (int i = 0; i < 2; i++)
#pragma unroll
        for (int n = 0; n < 8; n++) acc[i][n] = (f32x4){0,0,0,0};

    for (int stage = 0; stage < 2; stage++) {
        const float* Xg = x + ((size_t)b * LL + c0 + stage * 128) * FDIM;
#pragma unroll
        for (int g = 0; g < 2; g++) {
            const int lb = g * 64 + rh * 8;     // 8 consecutive rows per thread
            float4 v[8];
#pragma unroll
            for (int s = 0; s < 8; s++) v[s] = *(const float4*)&Xg[(size_t)(lb + s) * FDIM + f0];
            u16x8 hj[4];                        // transpose-pack: hj[j][s] = bf16(X[lb+s][f0+j])
#pragma unroll
            for (int s = 0; s < 8; s++) {
                int ci = stage * 128 + lb + s;
                float wq = cq[ci], wk = ck[ci];
                aq[0] += wq * v[s].x; aq[1] += wq * v[s].y; aq[2] += wq * v[s].z; aq[3] += wq * v[s].w;
                ak[0] += wk * v[s].x; ak[1] += wk * v[s].y; ak[2] += wk * v[s].z; ak[3] += wk * v[s].w;
                asv[0] += v[s].x; asv[1] += v[s].y; asv[2] += v[s].z; asv[3] += v[s].w;
                hj[0][s] = bfr(v[s].x); hj[1][s] = bfr(v[s].y);
                hj[2][s] = bfr(v[s].z); hj[3][s] = bfr(v[s].w);
            }
#pragma unroll
            for (int j = 0; j < 4; j++) {       // b128 write: 8 l's of row f0+j
                int f = f0 + j;
                *(u16x8*)((char*)XT + f * 256 + (swz(f, g * 8 + rh) << 4)) = hj[j];
            }
        }
        __syncthreads();
        // Gram accumulate over this stage's K=128 (4 phases)
#pragma unroll
        for (int k0 = 0; k0 < 128; k0 += 32) {
            bf16x8 a[2];
#pragma unroll
            for (int i = 0; i < 2; i++) {
                int fa = (wave * 2 + i) * 16 + l15;
                a[i] = *(const bf16x8*)((const char*)XT + fa * 256 + (swz(fa, (k0 >> 3) + quad) << 4));
            }
#pragma unroll
            for (int n = 0; n < 8; n++) {
                int gb = n * 16 + l15;
                bf16x8 bb = *(const bf16x8*)((const char*)XT + gb * 256 + (swz(gb, (k0 >> 3) + quad) << 4));
                acc[0][n] = __builtin_amdgcn_mfma_f32_16x16x32_bf16(a[0], bb, acc[0][n], 0, 0, 0);
                acc[1][n] = __builtin_amdgcn_mfma_f32_16x16x32_bf16(a[1], bb, acc[1][n], 0, 0, 0);
            }
        }
        __syncthreads();
    }
    // streaming Gram partial store (16 chunks/batch, no contention)
    float* Gp = ws + OFF_GP + ((size_t)cch * 32 + b) * 16384;
#pragma unroll
    for (int i = 0; i < 2; i++)
#pragma unroll
        for (int n = 0; n < 8; n++) {
            int g = n * 16 + l15;
#pragma unroll
            for (int reg = 0; reg < 4; reg++) {
                int f = (wave * 2 + i) * 16 + quad * 4 + reg;
                Gp[f * 128 + g] = acc[i][n][reg];
            }
        }
    // colsum partials (streamed, no atomics), reusing XT as float scratch [3][8][132]
    float* red = (float*)XT;
    *(f32x4*)&red[0 * 1056 + rh * 132 + f0] = aq;
    *(f32x4*)&red[1 * 1056 + rh * 132 + f0] = ak;
    *(f32x4*)&red[2 * 1056 + rh * 132 + f0] = asv;
    __syncthreads();
    if (tid < 128) {
#pragma unroll
        for (int p = 0; p < 3; p++) {
            float s = 0.f;
#pragma unroll
            for (int r = 0; r < 8; r++) s += red[p * 1056 + r * 132 + tid];
            ws[OFF_QP + (size_t)p * 65536 + (size_t)cch * 4096 + b * 128 + tid] = s;
        }
    }
}

// ---------------------------------------------------------------- reduce (unchanged from r6)
// grid 512, 256 threads. 16 Gram partials -> split-bf16 Gh/Gl swizzled images;
// blocks 0..11 also reduce the colsum partials.
__global__ __launch_bounds__(256) void reduce_kernel(float* __restrict__ ws) {
    const int tid = threadIdx.x;
    const size_t c0 = (size_t)blockIdx.x * 1024 + tid * 4;
    const float* Gp = ws + OFF_GP;
    f32x4 s = {0.f, 0.f, 0.f, 0.f};
#pragma unroll
    for (int ch = 0; ch < 16; ch++) {
        float4 u = *(const float4*)&Gp[(size_t)ch * 524288 + c0];
        s[0] += u.x; s[1] += u.y; s[2] += u.z; s[3] += u.w;
    }
    ushort4 gh, gl;
    gh.x = bfr(s[0]); gl.x = bfr(s[0] - b2f(gh.x));
    gh.y = bfr(s[1]); gl.y = bfr(s[1] - b2f(gh.y));
    gh.z = bfr(s[2]); gl.z = bfr(s[2] - b2f(gh.z));
    gh.w = bfr(s[3]); gl.w = bfr(s[3] - b2f(gh.w));
    const int bb = (int)(c0 >> 14), cell = (int)(c0 & 16383);
    const int a = cell >> 7, k0 = cell & 127;
    const size_t uidx = (size_t)bb * 16384 + a * 128 + (swz(a, k0 >> 3) << 3) + (k0 & 7);
    *(ushort4*)((unsigned short*)(ws + OFF_GH) + uidx) = gh;
    *(ushort4*)((unsigned short*)(ws + OFF_GL) + uidx) = gl;
    if (blockIdx.x < 12) {
        int o0 = blockIdx.x * 1024 + tid * 4;   // 0..12287
        int p = o0 >> 12, rem = o0 & 4095;
        const float* src = ws + OFF_QP + (size_t)p * 65536 + rem;
        f32x4 t = {0.f, 0.f, 0.f, 0.f};
#pragma unroll
        for (int ch = 0; ch < 16; ch++) {
            float4 u = *(const float4*)&src[ch * 4096];
            t[0] += u.x; t[1] += u.y; t[2] += u.z; t[3] += u.w;
        }
        *(f32x4*)&ws[OFF_QSUM + o0] = t;
    }
}

// ---------------------------------------------------------------- solve: per-batch fold to M', c'
// grid 32, 256 threads. G staged via batched vector loads + ds_write (NOT DMA);
// att phase parallelized across all 256 threads.
__global__ __launch_bounds__(256) void solve_kernel(const float* __restrict__ qw,
                                                    const float* __restrict__ qb,
                                                    const float* __restrict__ kw,
                                                    const float* __restrict__ kb,
                                                    const float* __restrict__ ffw,
                                                    const float* __restrict__ ffb,
                                                    const float* __restrict__ gamma,
                                                    const float* __restrict__ beta,
                                                    float* __restrict__ ws) {
    __shared__ __align__(16) unsigned short GhL[16384];
    __shared__ __align__(16) unsigned short GlL[16384];
    __shared__ __align__(16) unsigned short SA[16384];   // M1 row-major; later M2^T
    __shared__ __align__(16) unsigned short SB[16384];   // M1^T; later diag(a1)(I+W^T) image
    __shared__ float scr_k[128], scr_s[128], scr_a1[128], scr_b1[128], scr_a2[128];
    __shared__ float scr_vs[512];
    __shared__ float scr_mm[4];
    const int b = blockIdx.x, tid = threadIdx.x;
    const int wave = tid >> 6, lane = tid & 63, l15 = lane & 15, quad = lane >> 4;

    {   // stage Gh/Gl via batched vector loads + ds_write_b128 (swizzled image is linear here)
        const u16x8* gh = (const u16x8*)((const char*)ws + (size_t)OFF_GH * 4 + (size_t)b * 32768);
        const u16x8* gl = (const u16x8*)((const char*)ws + (size_t)OFF_GL * 4 + (size_t)b * 32768);
#pragma unroll
        for (int o = 0; o < 2; o++) {
            u16x8 tg[4], tl[4];
#pragma unroll
            for (int i = 0; i < 4; i++) {
                tg[i] = gh[(size_t)(o * 4 + i) * 256 + tid];
                tl[i] = gl[(size_t)(o * 4 + i) * 256 + tid];
            }
#pragma unroll
            for (int i = 0; i < 4; i++) {
                *(u16x8*)((char*)GhL + (o * 4 + i) * 4096 + tid * 16) = tg[i];
                *(u16x8*)((char*)GlL + (o * 4 + i) * 4096 + tid * 16) = tl[i];
            }
        }
    }
    // dq/dk (uniform recurrence)
    float dq = 0.f, dk = 0.f;
#pragma unroll
    for (int i = 0; i < NLEV; i++) {
        dq = (qw[2 * i] + qw[2 * i + 1]) * dq + qb[i];
        dk = (kw[2 * i] + kw[2 * i + 1]) * dk + kb[i];
    }
    const int f = tid & 127, half = tid >> 7;
    float qf = (ws[OFF_QSUM + b * FDIM + f] + dq) * SCL;
    if (tid < 128) {
        float kf = ws[OFF_QSUM + 4096 + b * FDIM + f] + dk;
        scr_k[f] = kf;
        scr_s[f] = ws[OFF_QSUM + 8192 + b * FDIM + f];
        float mx = kf, mn = kf;
#pragma unroll
        for (int off = 32; off; off >>= 1) {
            mx = fmaxf(mx, __shfl_xor(mx, off, 64));
            mn = fminf(mn, __shfl_xor(mn, off, 64));
        }
        if (lane == 0) { scr_mm[wave * 2] = mx; scr_mm[wave * 2 + 1] = mn; }
    }
    __syncthreads();
    float kmax = fmaxf(scr_mm[0], scr_mm[2]);
    float kmin = fminf(scr_mm[1], scr_mm[3]);

    // att (all 256 threads): thread (f, half) computes 64 of f's 128 exps
    {
        float m = (qf >= 0.f) ? qf * kmax : qf * kmin;
        float ssum = 0.f;
        for (int gi = half * 8; gi < half * 8 + 8; gi++) {
            u16x8 h;
#pragma unroll
            for (int j = 0; j < 8; j++) {
                float e = __expf(qf * scr_k[gi * 8 + j] - m);
                ssum += e;
                h[j] = bfr(e);
            }
            *(u16x8*)((char*)SA + f * 256 + (swz(f, gi) << 4)) = h;
        }
        scr_vs[tid] = ssum;
        __syncthreads();
        float sinv = 1.f / (scr_vs[f] + scr_vs[f + 128]);
        for (int gi = half * 8; gi < half * 8 + 8; gi++) {
            char* pa = (char*)SA + f * 256 + (swz(f, gi) << 4);
            u16x8 h = *(u16x8*)pa;
#pragma unroll
            for (int j = 0; j < 8; j++) {
                int g = gi * 8 + j;
                float v = b2f(h[j]) * sinv;
                if (g == f) v += 1.f;
                unsigned short u = bfr(v);
                h[j] = u;
                *(unsigned short*)((char*)SB + g * 256 + (swz(g, f >> 3) << 4) + (f & 7) * 2) = u;
            }
            *(u16x8*)pa = h;
        }
    }
    __syncthreads();

    // ---- P1 = (Gh+Gl) * M1 ; varsum1_g = diag(M1^T G M1)
    {
        f32x4 acc[2][8];
#pragma unroll
        for (int i = 0; i < 2; i++)
#pragma unroll
            for (int n = 0; n < 8; n++) acc[i][n] = (f32x4){0,0,0,0};
        for (int k0 = 0; k0 < 128; k0 += 32) {
            bf16x8 aH[2], aL[2];
#pragma unroll
            for (int i = 0; i < 2; i++) {
                int fa = (wave * 2 + i) * 16 + l15;
                int byte = fa * 256 + (swz(fa, (k0 >> 3) + quad) << 4);
                aH[i] = *(const bf16x8*)((const char*)GhL + byte);
                aL[i] = *(const bf16x8*)((const char*)GlL + byte);
            }
#pragma unroll
            for (int n = 0; n < 8; n++) {
                int gb = n * 16 + l15;
                bf16x8 bb = *(const bf16x8*)((const char*)SB + gb * 256 + (swz(gb, (k0 >> 3) + quad) << 4));
#pragma unroll
                for (int i = 0; i < 2; i++) {
                    acc[i][n] = __builtin_amdgcn_mfma_f32_16x16x32_bf16(aH[i], bb, acc[i][n], 0, 0, 0);
                    acc[i][n] = __builtin_amdgcn_mfma_f32_16x16x32_bf16(aL[i], bb, acc[i][n], 0, 0, 0);
                }
            }
        }
        float vsp[8];
#pragma unroll
        for (int n = 0; n < 8; n++) vsp[n] = 0.f;
#pragma unroll
        for (int i = 0; i < 2; i++)
#pragma unroll
            for (int n = 0; n < 8; n++) {
                int g = n * 16 + l15;
#pragma unroll
                for (int reg = 0; reg < 4; reg++) {
                    int fr = (wave * 2 + i) * 16 + quad * 4 + reg;
                    float m1 = b2f(*(const unsigned short*)((const char*)SA + fr * 256 + (swz(fr, g >> 3) << 4) + (g & 7) * 2));
                    vsp[n] += m1 * acc[i][n][reg];
                }
            }
#pragma unroll
        for (int n = 0; n < 8; n++) {
            float v = vsp[n];
            v += __shfl_xor(v, 16, 64); v += __shfl_xor(v, 32, 64);
            if (lane < 16) scr_vs[wave * 128 + n * 16 + lane] = v;
        }
    }
    __syncthreads();
    // stats1 -> a1, b1
    if (tid < 128) {
        const int g = tid;
        float vs = scr_vs[g] + scr_vs[128 + g] + scr_vs[256 + g] + scr_vs[384 + g];
        float tg = 0.f;
        for (int fb = 0; fb < 16; fb++) {
            u16x8 h = *(const u16x8*)((const char*)SB + g * 256 + (swz(g, fb) << 4));
#pragma unroll
            for (int j = 0; j < 8; j++) tg += scr_s[fb * 8 + j] * b2f(h[j]);
        }
        float mean = tg * (1.f / LL);
        float var  = vs * (1.f / LL) - mean * mean;
        float a1 = gamma[g] * rsqrtf(var + EPSF);
        scr_a1[g] = a1;
        scr_b1[g] = beta[g] - mean * a1;
    }
    __syncthreads();
    // stage SB = [diag(a1)(I+W^T)]^T image: SB[g][h] = a1_h * (W[g][h] + (g==h))
#pragma unroll
    for (int i = 0; i < 16; i++) {
        int idx4 = (tid + i * 256) * 4;
        int g = idx4 >> 7, h0 = idx4 & 127;
        float4 w = *(const float4*)&ffw[g * FDIM + h0];
        float v0 = (w.x + ((g == h0 + 0) ? 1.f : 0.f)) * scr_a1[h0 + 0];
        float v1 = (w.y + ((g == h0 + 1) ? 1.f : 0.f)) * scr_a1[h0 + 1];
        float v2 = (w.z + ((g == h0 + 2) ? 1.f : 0.f)) * scr_a1[h0 + 2];
        float v3 = (w.w + ((g == h0 + 3) ? 1.f : 0.f)) * scr_a1[h0 + 3];
        ushort4 h; h.x = bfr(v0); h.y = bfr(v1); h.z = bfr(v2); h.w = bfr(v3);
        *(ushort4*)((char*)SB + g * 256 + (swz(g, h0 >> 3) << 4) + (h0 & 7) * 2) = h;
    }
    __syncthreads();
    // ---- M2 = M1 * diag(a1)(I+W^T)
    {
        f32x4 accM[2][8];
#pragma unroll
        for (int i = 0; i < 2; i++)
#pragma unroll
            for (int n = 0; n < 8; n++) accM[i][n] = (f32x4){0,0,0,0};
        for (int k0 = 0; k0 < 128; k0 += 32) {
            bf16x8 a[2];
#pragma unroll
            for (int i = 0; i < 2; i++) {
                int fa = (wave * 2 + i) * 16 + l15;
                a[i] = *(const bf16x8*)((const char*)SA + fa * 256 + (swz(fa, (k0 >> 3) + quad) << 4));
            }
#pragma unroll
            for (int n = 0; n < 8; n++) {
                int gb = n * 16 + l15;
                bf16x8 bb = *(const bf16x8*)((const char*)SB + gb * 256 + (swz(gb, (k0 >> 3) + quad) << 4));
#pragma unroll
                for (int i = 0; i < 2; i++)
                    accM[i][n] = __builtin_amdgcn_mfma_f32_16x16x32_bf16(a[i], bb, accM[i][n], 0, 0, 0);
            }
        }
        __syncthreads();           // all M1 reads done; overwrite SA with M2^T
#pragma unroll
        for (int i = 0; i < 2; i++)
#pragma unroll
            for (int n = 0; n < 8; n++) {
                int g = n * 16 + l15;
#pragma unroll
                for (int reg = 0; reg < 4; reg++) {
                    int fr = (wave * 2 + i) * 16 + quad * 4 + reg;
                    *(unsigned short*)((char*)SA + g * 256 + (swz(g, fr >> 3) << 4) + (fr & 7) * 2) = bfr(accM[i][n][reg]);
                }
            }
    }
    __syncthreads();
    // ---- P2 = (Gh+Gl) * M2 ; varsum2_g = diag(M2^T G M2)
    {
        f32x4 acc[2][8];
#pragma unroll
        for (int i = 0; i < 2; i++)
#pragma unroll
            for (int n = 0; n < 8; n++) acc[i][n] = (f32x4){0,0,0,0};
        for (int k0 = 0; k0 < 128; k0 += 32) {
            bf16x8 aH[2], aL[2];
#pragma unroll
            for (int i = 0; i < 2; i++) {
                int fa = (wave * 2 + i) * 16 + l15;
                int byte = fa * 256 + (swz(fa, (k0 >> 3) + quad) << 4);
                aH[i] = *(const bf16x8*)((const char*)GhL + byte);
                aL[i] = *(const bf16x8*)((const char*)GlL + byte);
            }
#pragma unroll
            for (int n = 0; n < 8; n++) {
                int gb = n * 16 + l15;
                bf16x8 bb = *(const bf16x8*)((const char*)SA + gb * 256 + (swz(gb, (k0 >> 3) + quad) << 4));
#pragma unroll
                for (int i = 0; i < 2; i++) {
                    acc[i][n] = __builtin_amdgcn_mfma_f32_16x16x32_bf16(aH[i], bb, acc[i][n], 0, 0, 0);
                    acc[i][n] = __builtin_amdgcn_mfma_f32_16x16x32_bf16(aL[i], bb, acc[i][n], 0, 0, 0);
                }
            }
        }
        float vsp[8];
#pragma unroll
        for (int n = 0; n < 8; n++) vsp[n] = 0.f;
#pragma unroll
        for (int i = 0; i < 2; i++)
#pragma unroll
            for (int n = 0; n < 8; n++) {
                int g = n * 16 + l15;
#pragma unroll
                for (int reg = 0; reg < 4; reg++) {
                    int fr = (wave * 2 + i) * 16 + quad * 4 + reg;
                    float m2 = b2f(*(const unsigned short*)((const char*)SA + g * 256 + (swz(g, fr >> 3) << 4) + (fr & 7) * 2));
                    vsp[n] += m2 * acc[i][n][reg];
                }
            }
#pragma unroll
        for (int n = 0; n < 8; n++) {
            float v = vsp[n];
            v += __shfl_xor(v, 16, 64); v += __shfl_xor(v, 32, 64);
            if (lane < 16) scr_vs[wave * 128 + n * 16 + lane] = v;
        }
    }
    __syncthreads();
    // stats2 -> a2, c'
    if (tid < 128) {
        const int g = tid;
        float vs = scr_vs[g] + scr_vs[128 + g] + scr_vs[256 + g] + scr_vs[384 + g];
        float t2 = 0.f;
        for (int fb = 0; fb < 16; fb++) {
            u16x8 h = *(const u16x8*)((const char*)SA + g * 256 + (swz(g, fb) << 4));
#pragma unroll
            for (int j = 0; j < 8; j++) t2 += scr_s[fb * 8 + j] * b2f(h[j]);
        }
        float c2 = ffb[g] + scr_b1[g];
        for (int hb = 0; hb < 32; hb++) {
            float4 w = *(const float4*)&ffw[g * FDIM + hb * 4];
            c2 += scr_b1[hb * 4 + 0] * w.x + scr_b1[hb * 4 + 1] * w.y
                + scr_b1[hb * 4 + 2] * w.z + scr_b1[hb * 4 + 3] * w.w;
        }
        float mean2 = t2 * (1.f / LL) + c2;
        float ey2   = vs * (1.f / LL) + 2.f * c2 * t2 * (1.f / LL) + c2 * c2;
        float var2  = ey2 - mean2 * mean2;
        float a2 = gamma[g] * rsqrtf(var2 + EPSF);
        scr_a2[g] = a2;
        ws[OFF_CP + b * FDIM + g] = a2 * (c2 - mean2) + beta[g];
    }
    __syncthreads();
    // M'^T = a2-scaled M2^T -> global MP (same swizzled byte image as LDS)
    {
        unsigned short* MP = (unsigned short*)(ws + OFF_MP) + (size_t)b * 16384;
        const int g = tid >> 1, hf = (tid & 1) * 8;
        float a2 = scr_a2[g];
        for (int s = 0; s < 8; s++) {
            int slot = hf + s;
            u16x8 h = *(const u16x8*)((const char*)SA + g * 256 + slot * 16);
#pragma unroll
            for (int j = 0; j < 8; j++) h[j] = bfr(b2f(h[j]) * a2);
            *(u16x8*)&MP[g * 128 + slot * 8] = h;
        }
    }
}

// ---------------------------------------------------------------- out = X * M' + c' (unchanged from r6)
// grid (64, 32), 256 threads, 64-row tiles; X fp32 (L3-hot), M' via LDS DMA.
__global__ __launch_bounds__(256) void outgemm_kernel(const float* __restrict__ x,
                                                      const float* __restrict__ ws,
                                                      float* __restrict__ out) {
    __shared__ __align__(16) unsigned short Xs[64][136];
    __shared__ __align__(16) unsigned short Bs[16384];
    __shared__ float cps[128];
    const int b = blockIdx.y, r0 = blockIdx.x * 64, tid = threadIdx.x;
    const char* mp = (const char*)ws + (size_t)OFF_MP * 4 + (size_t)b * 32768;
#pragma unroll
    for (int i = 0; i < 8; i++)
        ldsload16((char*)Bs + i * 4096 + tid * 16, mp + i * 4096 + tid * 16);
    const float* Xg = x + (size_t)b * LL * FDIM + (size_t)r0 * FDIM;
#pragma unroll
    for (int i = 0; i < 8; i++) {
        int idx4 = (tid + i * 256) * 4;
        int r = idx4 >> 7, c = idx4 & 127;
        float4 v = *(const float4*)&Xg[r * FDIM + c];
        ushort4 h; h.x = bfr(v.x); h.y = bfr(v.y); h.z = bfr(v.z); h.w = bfr(v.w);
        *(ushort4*)&Xs[r][c] = h;
    }
    if (tid < 128) cps[tid] = ws[OFF_CP + b * FDIM + tid];
    __syncthreads();
    const int wave = tid >> 6, lane = tid & 63, l15 = lane & 15, quad = lane >> 4;
    const int rowA = wave * 16 + l15;
    f32x4 acc[8];
#pragma unroll
    for (int t = 0; t < 8; t++) acc[t] = (f32x4){0,0,0,0};
#pragma unroll
    for (int k0 = 0; k0 < 128; k0 += 32) {
        bf16x8 a = *(const bf16x8*)&Xs[rowA][k0 + quad * 8];
#pragma unroll
        for (int t = 0; t < 8; t++) {
            int gb = t * 16 + l15;
            bf16x8 bb = *(const bf16x8*)((const char*)Bs + gb * 256 + (swz(gb, (k0 >> 3) + quad) << 4));
            acc[t] = __builtin_amdgcn_mfma_f32_16x16x32_bf16(a, bb, acc[t], 0, 0, 0);
        }
    }
    float* Ob = out + ((size_t)b * LL + r0) * FDIM;
#pragma unroll
    for (int t = 0; t < 8; t++) {
        int col = t * 16 + l15;
        float cp = cps[col];
#pragma unroll
        for (int reg = 0; reg < 4; reg++)
            Ob[(wave * 16 + quad * 4 + reg) * FDIM + col] = acc[t][reg] + cp;
    }
}

extern "C" void kernel_launch(void* const* d_in, const int* in_sizes, int n_in,
                              void* d_out, int out_size, void* d_ws, size_t ws_size,
                              hipStream_t stream) {
    const float* x     = (const float*)d_in[0];
    const float* q_w   = (const float*)d_in[1];
    const float* q_b   = (const float*)d_in[2];
    const float* k_w   = (const float*)d_in[3];
    const float* k_b   = (const float*)d_in[4];
    const float* ff_w  = (const float*)d_in[5];
    const float* ff_b  = (const float*)d_in[6];
    const float* gamma = (const float*)d_in[7];
    const float* beta  = (const float*)d_in[8];
    float* out = (float*)d_out;
    float* ws  = (float*)d_ws;

    pass1_kernel<<<dim3(16, 32), 256, 0, stream>>>(x, q_w, k_w, ws);
    reduce_kernel<<<512, 256, 0, stream>>>(ws);
    solve_kernel<<<32, 256, 0, stream>>>(q_w, q_b, k_w, k_b, ff_w, ff_b, gamma, beta, ws);
    outgemm_kernel<<<dim3(64, 32), 256, 0, stream>>>(x, ws, out);
}